// Round 1
// baseline (1755.347 us; speedup 1.0000x reference)
//
#include <hip/hip_runtime.h>
#include <math.h>

#define Bb_ 32
#define Nn_ 512
#define Ff_ 32
#define Tt_ 24
#define GC_ 64
#define TC_ 64

__device__ __forceinline__ float sigmoidf_(float v) { return 1.0f / (1.0f + __expf(-v)); }

// ---------------- temporal attention pieces ----------------
// tmp[b,t,f] = sum_n x[b,n,f,t] * w1[n]
__global__ void ka_tmp(const float* __restrict__ x, const float* __restrict__ w1,
                       float* __restrict__ tmp) {
    int tid = blockIdx.x * blockDim.x + threadIdx.x;   // B*F*T = 24576
    int t = tid % Tt_;
    int f = (tid / Tt_) % Ff_;
    int b = tid / (Tt_ * Ff_);
    const float* xp = x + ((size_t)b * Nn_ * Ff_ + f) * Tt_ + t;
    float s = 0.f;
    for (int n = 0; n < Nn_; ++n) s += xp[(size_t)n * Ff_ * Tt_] * w1[n];
    tmp[(b * Tt_ + t) * Ff_ + f] = s;
}

// rhs_t[b,n,t] = sum_f w3[f] * x[b,n,f,t]
__global__ void kb_rhs(const float* __restrict__ x, const float* __restrict__ w3,
                       float* __restrict__ rhs_t) {
    int tid = blockIdx.x * blockDim.x + threadIdx.x;   // B*N*T
    int t = tid % Tt_;
    int n = (tid / Tt_) % Nn_;
    int b = tid / (Tt_ * Nn_);
    const float* xp = x + (((size_t)b * Nn_ + n) * Ff_) * Tt_ + t;
    float s = 0.f;
#pragma unroll
    for (int f = 0; f < Ff_; ++f) s += w3[f] * xp[f * Tt_];
    rhs_t[(b * Nn_ + n) * Tt_ + t] = s;
}

// lhs_t[b,t,n] = sum_f tmp[b,t,f] * w2[f,n]
__global__ void kc_lhs(const float* __restrict__ tmp, const float* __restrict__ w2,
                       float* __restrict__ lhs_t) {
    int tid = blockIdx.x * blockDim.x + threadIdx.x;   // B*T*N
    int n = tid % Nn_;
    int t = (tid / Nn_) % Tt_;
    int b = tid / (Nn_ * Tt_);
    const float* tp = tmp + (b * Tt_ + t) * Ff_;
    float s = 0.f;
#pragma unroll
    for (int f = 0; f < Ff_; ++f) s += tp[f] * w2[f * Nn_ + n];
    lhs_t[(b * Tt_ + t) * Nn_ + n] = s;
}

// per-batch: prod -> sigmoid -> E = proj @ sig -> softmax over s -> temp_w
__global__ __launch_bounds__(576) void kd_temporal(const float* __restrict__ lhs_t,
                                                   const float* __restrict__ rhs_t,
                                                   const float* __restrict__ ta_bias,
                                                   const float* __restrict__ ta_proj,
                                                   float* __restrict__ temp_w) {
    __shared__ float rl[Nn_ * Tt_];   // 12288
    __shared__ float sg[Tt_ * Tt_];   // 576
    __shared__ float Eb[Tt_ * Tt_];   // 576
    int b = blockIdx.x;
    int tid = threadIdx.x;
    for (int i = tid; i < Nn_ * Tt_; i += 576) rl[i] = rhs_t[b * Nn_ * Tt_ + i];
    __syncthreads();
    int u = tid % Tt_;
    int t = tid / Tt_;   // 0..23
    const float* lp = lhs_t + (b * Tt_ + t) * Nn_;
    float s = 0.f;
    for (int n = 0; n < Nn_; ++n) s += lp[n] * rl[n * Tt_ + u];
    sg[t * Tt_ + u] = sigmoidf_(s + ta_bias[t * Tt_ + u]);
    __syncthreads();
    float e = 0.f;
#pragma unroll
    for (int k = 0; k < Tt_; ++k) e += ta_proj[t * Tt_ + k] * sg[k * Tt_ + u];
    Eb[t * Tt_ + u] = e;
    __syncthreads();
    if (tid < Tt_) {
        int uu = tid;
        float m = -1e30f;
        for (int s2 = 0; s2 < Tt_; ++s2) m = fmaxf(m, Eb[s2 * Tt_ + uu]);
        float sum = 0.f;
        for (int s2 = 0; s2 < Tt_; ++s2) sum += __expf(Eb[s2 * Tt_ + uu] - m);
        float inv = 1.0f / sum;
        for (int s2 = 0; s2 < Tt_; ++s2)
            temp_w[b * Tt_ * Tt_ + s2 * Tt_ + uu] = __expf(Eb[s2 * Tt_ + uu] - m) * inv;
    }
}

// per (b,n): x_temp row (in LDS only) -> lhs_s, rhs_s
__global__ __launch_bounds__(256) void ke_spatial(const float* __restrict__ x,
                                                  const float* __restrict__ tw,
                                                  const float* __restrict__ sa_wa,
                                                  const float* __restrict__ sa_wb,
                                                  const float* __restrict__ sa_wc,
                                                  float* __restrict__ lhs_s,
                                                  float* __restrict__ rhs_s) {
    __shared__ float xl[Ff_ * Tt_];    // 768
    __shared__ float twl[Tt_ * Tt_];   // 576
    __shared__ float xtl[Ff_ * Tt_];   // 768
    __shared__ float tmp2[Ff_];
    int n = blockIdx.x, b = blockIdx.y, tid = threadIdx.x;
    const float* xp = x + ((size_t)(b * Nn_ + n)) * Ff_ * Tt_;
    for (int i = tid; i < Ff_ * Tt_; i += 256) xl[i] = xp[i];
    for (int i = tid; i < Tt_ * Tt_; i += 256) twl[i] = tw[b * Tt_ * Tt_ + i];
    __syncthreads();
    for (int i = tid; i < Ff_ * Tt_; i += 256) {
        int f = i / Tt_, u = i % Tt_;
        float s = 0.f;
#pragma unroll
        for (int t = 0; t < Tt_; ++t) s += xl[f * Tt_ + t] * twl[t * Tt_ + u];
        xtl[i] = s;
    }
    __syncthreads();
    if (tid < Ff_) {
        float s = 0.f;
#pragma unroll
        for (int t = 0; t < Tt_; ++t) s += xtl[tid * Tt_ + t] * sa_wa[t];
        tmp2[tid] = s;
    }
    __syncthreads();
    if (tid < Tt_) {
        float a = 0.f, r = 0.f;
#pragma unroll
        for (int f = 0; f < Ff_; ++f) {
            a += tmp2[f] * sa_wb[f * Tt_ + tid];
            r += sa_wc[f] * xtl[f * Tt_ + tid];
        }
        int o = (b * Nn_ + n) * Tt_ + tid;
        lhs_s[o] = a;
        rhs_s[o] = r;
    }
}

// attn[b,n,m] = sigmoid( lhs_s[b,n,:] . rhs_s[b,m,:] + sa_bias[n,m] )
__global__ __launch_bounds__(256) void kg_attn(const float* __restrict__ lhs_s,
                                               const float* __restrict__ rhs_s,
                                               const float* __restrict__ sa_bias,
                                               float* __restrict__ attn) {
    __shared__ float rl[Nn_ * 25];   // padded stride 25 -> conflict-free
    __shared__ float ll[16 * Tt_];
    int b = blockIdx.y;
    int n0 = blockIdx.x * 16;
    int tid = threadIdx.x;
    for (int i = tid; i < Nn_ * Tt_; i += 256) {
        int m = i / Tt_, t = i % Tt_;
        rl[m * 25 + t] = rhs_s[b * Nn_ * Tt_ + i];
    }
    for (int i = tid; i < 16 * Tt_; i += 256) ll[i] = lhs_s[b * Nn_ * Tt_ + n0 * Tt_ + i];
    __syncthreads();
    for (int idx = tid; idx < 16 * Nn_; idx += 256) {
        int r = idx >> 9;          // /512
        int m = idx & (Nn_ - 1);
        const float* lp = ll + r * Tt_;
        const float* rp = rl + m * 25;
        float s = 0.f;
#pragma unroll
        for (int t = 0; t < Tt_; ++t) s += lp[t] * rp[t];
        int n = n0 + r;
        attn[((size_t)b * Nn_ + n) * Nn_ + m] = sigmoidf_(s + sa_bias[n * Nn_ + m]);
    }
}

// S[b] = proj @ attn[b]   (512x512x512, fp32 tiled)
__global__ __launch_bounds__(256) void kh_sgemm(const float* __restrict__ proj,
                                                const float* __restrict__ attn,
                                                float* __restrict__ S) {
    __shared__ float As[16 * 68];   // [kk][r], stride 68 (16B-aligned rows, bank-shifted)
    __shared__ float Bs[16 * 64];   // [kk][c]
    int b = blockIdx.z;
    int row0 = blockIdx.y * 64, col0 = blockIdx.x * 64;
    int tid = threadIdx.x, tx = tid & 15, ty = tid >> 4;
    const float* Bbase = attn + (size_t)b * Nn_ * Nn_;
    float acc[4][4] = {{0.f}};
    int lr = tid >> 2, lq = tid & 3;     // A: row lr, kk = lq*4..
    int bk = tid >> 4, bq = tid & 15;    // B: kk = bk, col = bq*4..
    for (int k0 = 0; k0 < Nn_; k0 += 16) {
        float4 av = *(const float4*)(proj + (size_t)(row0 + lr) * Nn_ + k0 + lq * 4);
        As[(lq * 4 + 0) * 68 + lr] = av.x;
        As[(lq * 4 + 1) * 68 + lr] = av.y;
        As[(lq * 4 + 2) * 68 + lr] = av.z;
        As[(lq * 4 + 3) * 68 + lr] = av.w;
        float4 bv = *(const float4*)(Bbase + (size_t)(k0 + bk) * Nn_ + col0 + bq * 4);
        *(float4*)(Bs + bk * 64 + bq * 4) = bv;
        __syncthreads();
#pragma unroll
        for (int kk = 0; kk < 16; ++kk) {
            float4 a4 = *(const float4*)(As + kk * 68 + ty * 4);
            float4 b4 = *(const float4*)(Bs + kk * 64 + tx * 4);
            float aa[4] = {a4.x, a4.y, a4.z, a4.w};
            float bbv[4] = {b4.x, b4.y, b4.z, b4.w};
#pragma unroll
            for (int i = 0; i < 4; ++i)
#pragma unroll
                for (int j = 0; j < 4; ++j) acc[i][j] += aa[i] * bbv[j];
        }
        __syncthreads();
    }
    float* Cb = S + (size_t)b * Nn_ * Nn_;
#pragma unroll
    for (int i = 0; i < 4; ++i) {
        float4 v = make_float4(acc[i][0], acc[i][1], acc[i][2], acc[i][3]);
        *(float4*)(Cb + (size_t)(row0 + ty * 4 + i) * Nn_ + col0 + tx * 4) = v;
    }
}

// column softmax over n of S[b,n,p], in place
__global__ void kj_softmax(float* __restrict__ S) {
    int b = blockIdx.y;
    int p = blockIdx.x * 64 + threadIdx.x;
    float* Sp = S + (size_t)b * Nn_ * Nn_ + p;
    float m = -1e30f, s = 0.f;
    for (int n = 0; n < Nn_; ++n) {
        float v = Sp[(size_t)n * Nn_];
        float nm = fmaxf(m, v);
        s = s * __expf(m - nm) + __expf(v - nm);
        m = nm;
    }
    float inv = 1.0f / s;
    for (int n = 0; n < Nn_; ++n) Sp[(size_t)n * Nn_] = __expf(Sp[(size_t)n * Nn_] - m) * inv;
}

// h[b,n,c] = sum_m (cheb_k[m,n]*spat[b,m,n]) * x[b,m,c]   (c = f*T+t, 768 wide)
__global__ __launch_bounds__(256) void kh_hgemm(const float* __restrict__ cheb,
                                                const float* __restrict__ spat,
                                                const float* __restrict__ x,
                                                float* __restrict__ h, int k) {
    __shared__ float As[16 * 64];   // [kk][n]
    __shared__ float Bs[16 * 64];   // [kk][c]
    int b = blockIdx.z;
    int col0 = blockIdx.x * 64;   // 0..768
    int row0 = blockIdx.y * 64;   // 0..512
    int tid = threadIdx.x, tx = tid & 15, ty = tid >> 4;
    int lk = tid >> 4, lq = tid & 15;
    const float* Ck = cheb + (size_t)k * Nn_ * Nn_;
    const float* Sb = spat + (size_t)b * Nn_ * Nn_;
    const float* Xb = x + (size_t)b * Nn_ * (Ff_ * Tt_);
    float acc[4][4] = {{0.f}};
    for (int k0 = 0; k0 < Nn_; k0 += 16) {
        int m = k0 + lk;
        float4 cv = *(const float4*)(Ck + (size_t)m * Nn_ + row0 + lq * 4);
        float4 sv = *(const float4*)(Sb + (size_t)m * Nn_ + row0 + lq * 4);
        float4 av = make_float4(cv.x * sv.x, cv.y * sv.y, cv.z * sv.z, cv.w * sv.w);
        *(float4*)(As + lk * 64 + lq * 4) = av;
        float4 bv = *(const float4*)(Xb + (size_t)m * (Ff_ * Tt_) + col0 + lq * 4);
        *(float4*)(Bs + lk * 64 + lq * 4) = bv;
        __syncthreads();
#pragma unroll
        for (int kk = 0; kk < 16; ++kk) {
            float4 a4 = *(const float4*)(As + kk * 64 + ty * 4);
            float4 b4 = *(const float4*)(Bs + kk * 64 + tx * 4);
            float aa[4] = {a4.x, a4.y, a4.z, a4.w};
            float bbv[4] = {b4.x, b4.y, b4.z, b4.w};
#pragma unroll
            for (int i = 0; i < 4; ++i)
#pragma unroll
                for (int j = 0; j < 4; ++j) acc[i][j] += aa[i] * bbv[j];
        }
        __syncthreads();
    }
    float* Hb = h + (size_t)b * Nn_ * (Ff_ * Tt_);
#pragma unroll
    for (int i = 0; i < 4; ++i) {
        float4 v = make_float4(acc[i][0], acc[i][1], acc[i][2], acc[i][3]);
        *(float4*)(Hb + (size_t)(row0 + ty * 4 + i) * (Ff_ * Tt_) + col0 + tx * 4) = v;
    }
}

// y[b,n,o,t] (+)= sum_f h[b,n,f,t] * w_cheb[k,f,o] ; mode2 adds + relu
__global__ __launch_bounds__(256) void kacc(const float* __restrict__ h,
                                            const float* __restrict__ wch,
                                            float* __restrict__ y, int k, int mode) {
    __shared__ float hl[Ff_ * Tt_];    // 768
    __shared__ float wl[Ff_ * GC_];    // 2048
    int n = blockIdx.x, b = blockIdx.y, tid = threadIdx.x;
    const float* hp = h + ((size_t)(b * Nn_ + n)) * Ff_ * Tt_;
    for (int i = tid; i < Ff_ * Tt_; i += 256) hl[i] = hp[i];
    for (int i = tid; i < Ff_ * GC_; i += 256) wl[i] = wch[k * Ff_ * GC_ + i];
    __syncthreads();
    float* yp = y + ((size_t)(b * Nn_ + n)) * GC_ * Tt_;
    for (int idx = tid; idx < GC_ * Tt_; idx += 256) {
        int o = idx / Tt_, t = idx % Tt_;
        float s = 0.f;
#pragma unroll
        for (int f = 0; f < Ff_; ++f) s += hl[f * Tt_ + t] * wl[f * GC_ + o];
        if (mode == 0)
            yp[idx] = s;
        else if (mode == 1)
            yp[idx] += s;
        else {
            float v = yp[idx] + s;
            yp[idx] = v > 0.f ? v : 0.f;
        }
    }
}

// in-place 1x3 conv over t on gcn rows (time_w only; bias added in kk2)
__global__ __launch_bounds__(128) void kk1_conv(float* __restrict__ y,
                                                const float* __restrict__ time_w) {
    __shared__ float twl[GC_ * 3 * TC_];        // [(g*3+j)][c] = 12288
    __shared__ float gl[2][GC_ * 26 + 8];       // [sub][g*26 + tau], tau=t+1, zero borders
    int b = blockIdx.y;
    int n_base = blockIdx.x * 16;
    int tid = threadIdx.x;
    int sub = tid >> 6;
    int c = tid & 63;
    for (int i = tid; i < GC_ * 3 * TC_; i += 128) {
        int cc = i / (GC_ * 3);
        int r = i % (GC_ * 3);
        twl[r * TC_ + cc] = time_w[i];   // time_w flat [c][g][j]
    }
    for (int g = c; g < GC_; g += 64) {
        gl[sub][g * 26 + 0] = 0.f;
        gl[sub][g * 26 + 25] = 0.f;
    }
    __syncthreads();
    for (int it = 0; it < 8; ++it) {
        int n = n_base + it * 2 + sub;
        float* yp = y + ((size_t)(b * Nn_ + n)) * GC_ * Tt_;
        for (int i = c; i < GC_ * Tt_; i += 64) {
            int g = i / Tt_, t = i % Tt_;
            gl[sub][g * 26 + t + 1] = yp[i];
        }
        __syncthreads();
        float acc[Tt_];
#pragma unroll
        for (int t = 0; t < Tt_; ++t) acc[t] = 0.f;
        for (int g = 0; g < GC_; ++g) {
            float w0 = twl[(g * 3 + 0) * TC_ + c];
            float w1 = twl[(g * 3 + 1) * TC_ + c];
            float w2 = twl[(g * 3 + 2) * TC_ + c];
            const float* gp = &gl[sub][g * 26];
            float a = gp[0], bb2 = gp[1];
#pragma unroll
            for (int t = 0; t < Tt_; ++t) {
                float cc2 = gp[t + 2];
                acc[t] += w0 * a + w1 * bb2 + w2 * cc2;
                a = bb2;
                bb2 = cc2;
            }
        }
#pragma unroll
        for (int t = 0; t < Tt_; ++t) yp[c * Tt_ + t] = acc[t];
        __syncthreads();
    }
}

// skip(1x1) + biases + relu + layernorm(over c) + transposed store to out[b,n,c,t]
__global__ __launch_bounds__(256) void kk2_ln(const float* __restrict__ pre,
                                              const float* __restrict__ x,
                                              const float* __restrict__ skip_w,
                                              const float* __restrict__ time_b,
                                              const float* __restrict__ skip_b,
                                              const float* __restrict__ ln_g,
                                              const float* __restrict__ ln_b,
                                              float* __restrict__ out) {
    __shared__ float pl[TC_ * Tt_];    // [c][t]
    __shared__ float xl[Ff_ * Tt_];    // [f][t]
    __shared__ float swl[Ff_ * TC_];   // [f][c]
    __shared__ float bias0[TC_], lg[TC_], lb[TC_];
    int n = blockIdx.x, b = blockIdx.y, tid = threadIdx.x;
    const float* pp = pre + ((size_t)(b * Nn_ + n)) * TC_ * Tt_;
    for (int i = tid; i < TC_ * Tt_; i += 256) pl[i] = pp[i];
    const float* xp = x + ((size_t)(b * Nn_ + n)) * Ff_ * Tt_;
    for (int i = tid; i < Ff_ * Tt_; i += 256) xl[i] = xp[i];
    for (int i = tid; i < Ff_ * TC_; i += 256) {
        int f = i >> 6, cc = i & 63;
        swl[i] = skip_w[cc * Ff_ + f];
    }
    if (tid < TC_) {
        bias0[tid] = time_b[tid] + skip_b[tid];
        lg[tid] = ln_g[tid];
        lb[tid] = ln_b[tid];
    }
    __syncthreads();
    int c = tid & 63, tg = tid >> 6;   // wave = one tg
    float sv[6];
#pragma unroll
    for (int ti = 0; ti < 6; ++ti) sv[ti] = pl[c * Tt_ + (tg + ti * 4)] + bias0[c];
    for (int f = 0; f < Ff_; ++f) {
        float w = swl[f * TC_ + c];
#pragma unroll
        for (int ti = 0; ti < 6; ++ti) sv[ti] += w * xl[f * Tt_ + tg + ti * 4];
    }
#pragma unroll
    for (int ti = 0; ti < 6; ++ti) {
        float v = sv[ti] > 0.f ? sv[ti] : 0.f;
        float sum = v, sq = v * v;
#pragma unroll
        for (int off = 32; off > 0; off >>= 1) {
            sum += __shfl_xor(sum, off, 64);
            sq += __shfl_xor(sq, off, 64);
        }
        float mu = sum * (1.0f / 64.0f);
        float var = sq * (1.0f / 64.0f) - mu * mu;
        float r = rsqrtf(var + 1e-5f);
        int t = tg + ti * 4;
        out[(((size_t)(b * Nn_ + n)) * TC_ + c) * Tt_ + t] = (v - mu) * r * lg[c] + lb[c];
    }
}

extern "C" void kernel_launch(void* const* d_in, const int* in_sizes, int n_in,
                              void* d_out, int out_size, void* d_ws, size_t ws_size,
                              hipStream_t stream) {
    const float* x       = (const float*)d_in[0];
    const float* cheb    = (const float*)d_in[1];
    const float* w_cheb  = (const float*)d_in[2];
    const float* sa_wa   = (const float*)d_in[3];
    const float* sa_wb   = (const float*)d_in[4];
    const float* sa_wc   = (const float*)d_in[5];
    const float* sa_bias = (const float*)d_in[6];
    const float* sa_proj = (const float*)d_in[7];
    const float* ta_w1   = (const float*)d_in[8];
    const float* ta_w2   = (const float*)d_in[9];
    const float* ta_w3   = (const float*)d_in[10];
    const float* ta_bias = (const float*)d_in[11];
    const float* ta_proj = (const float*)d_in[12];
    const float* time_w  = (const float*)d_in[13];
    const float* time_b  = (const float*)d_in[14];
    const float* skip_w  = (const float*)d_in[15];
    const float* skip_b  = (const float*)d_in[16];
    const float* ln_g    = (const float*)d_in[17];
    const float* ln_b    = (const float*)d_in[18];
    float* out = (float*)d_out;

    float* ws    = (float*)d_ws;
    float* tmp   = ws;                   // 24576
    float* lhs_t = tmp + 24576;          // 393216
    float* rhs_t = lhs_t + 393216;       // 393216
    float* tw    = rhs_t + 393216;       // 18432
    float* lhs_s = tw + 18432;           // 393216
    float* rhs_s = lhs_s + 393216;       // 393216
    float* attn  = rhs_s + 393216;       // 8388608
    float* Sbuf  = attn + 8388608;       // 8388608
    float* hbuf  = Sbuf + 8388608;       // 12582912
    float* ybuf  = hbuf + 12582912;      // 25165824  (total ~224.6 MB)

    ka_tmp<<<96, 256, 0, stream>>>(x, ta_w1, tmp);
    kb_rhs<<<1536, 256, 0, stream>>>(x, ta_w3, rhs_t);
    kc_lhs<<<1536, 256, 0, stream>>>(tmp, ta_w2, lhs_t);
    kd_temporal<<<32, 576, 0, stream>>>(lhs_t, rhs_t, ta_bias, ta_proj, tw);
    ke_spatial<<<dim3(512, 32), 256, 0, stream>>>(x, tw, sa_wa, sa_wb, sa_wc, lhs_s, rhs_s);
    kg_attn<<<dim3(32, 32), 256, 0, stream>>>(lhs_s, rhs_s, sa_bias, attn);
    kh_sgemm<<<dim3(8, 8, 32), 256, 0, stream>>>(sa_proj, attn, Sbuf);
    kj_softmax<<<dim3(8, 32), 64, 0, stream>>>(Sbuf);
    for (int k = 0; k < 3; ++k) {
        kh_hgemm<<<dim3(12, 8, 32), 256, 0, stream>>>(cheb, Sbuf, x, hbuf, k);
        kacc<<<dim3(512, 32), 256, 0, stream>>>(hbuf, w_cheb, ybuf, k,
                                                k == 0 ? 0 : (k == 2 ? 2 : 1));
    }
    kk1_conv<<<dim3(32, 32), 128, 0, stream>>>(ybuf, time_w);
    kk2_ln<<<dim3(512, 32), 256, 0, stream>>>(ybuf, x, skip_w, time_b, skip_b, ln_g, ln_b, out);
}

// Round 2
// 1310.581 us; speedup vs baseline: 1.3394x; 1.3394x over previous
//
#include <hip/hip_runtime.h>
#include <math.h>

#define Bb_ 32
#define Nn_ 512
#define Ff_ 32
#define Tt_ 24
#define GC_ 64
#define TC_ 64

typedef __attribute__((ext_vector_type(8))) short bf16x8;
typedef __attribute__((ext_vector_type(4))) float f32x4;

__device__ __forceinline__ float sigmoidf_(float v) { return 1.0f / (1.0f + __expf(-v)); }

__device__ __forceinline__ unsigned short f2bf(float f) {
    unsigned u = __float_as_uint(f);
    u = (u + 0x7fffu + ((u >> 16) & 1u)) >> 16;
    return (unsigned short)u;
}
__device__ __forceinline__ float bf2f(unsigned short h) {
    return __uint_as_float(((unsigned)h) << 16);
}

__device__ __forceinline__ void async16(const void* g, void* l) {
    __builtin_amdgcn_global_load_lds((const __attribute__((address_space(1))) unsigned int*)g,
                                     (__attribute__((address_space(3))) unsigned int*)l,
                                     16, 0, 0);
}

// ---------------- temporal attention pieces ----------------
__global__ void ka_tmp(const float* __restrict__ x, const float* __restrict__ w1,
                       float* __restrict__ tmp) {
    int tid = blockIdx.x * blockDim.x + threadIdx.x;
    int t = tid % Tt_;
    int f = (tid / Tt_) % Ff_;
    int b = tid / (Tt_ * Ff_);
    const float* xp = x + ((size_t)b * Nn_ * Ff_ + f) * Tt_ + t;
    float s = 0.f;
    for (int n = 0; n < Nn_; ++n) s += xp[(size_t)n * Ff_ * Tt_] * w1[n];
    tmp[(b * Tt_ + t) * Ff_ + f] = s;
}

__global__ void kb_rhs(const float* __restrict__ x, const float* __restrict__ w3,
                       float* __restrict__ rhs_t) {
    int tid = blockIdx.x * blockDim.x + threadIdx.x;
    int t = tid % Tt_;
    int n = (tid / Tt_) % Nn_;
    int b = tid / (Tt_ * Nn_);
    const float* xp = x + (((size_t)b * Nn_ + n) * Ff_) * Tt_ + t;
    float s = 0.f;
#pragma unroll
    for (int f = 0; f < Ff_; ++f) s += w3[f] * xp[f * Tt_];
    rhs_t[(b * Nn_ + n) * Tt_ + t] = s;
}

__global__ void kc_lhs(const float* __restrict__ tmp, const float* __restrict__ w2,
                       float* __restrict__ lhs_t) {
    int tid = blockIdx.x * blockDim.x + threadIdx.x;
    int n = tid % Nn_;
    int t = (tid / Nn_) % Tt_;
    int b = tid / (Nn_ * Tt_);
    const float* tp = tmp + (b * Tt_ + t) * Ff_;
    float s = 0.f;
#pragma unroll
    for (int f = 0; f < Ff_; ++f) s += tp[f] * w2[f * Nn_ + n];
    lhs_t[(b * Tt_ + t) * Nn_ + n] = s;
}

__global__ __launch_bounds__(576) void kd_temporal(const float* __restrict__ lhs_t,
                                                   const float* __restrict__ rhs_t,
                                                   const float* __restrict__ ta_bias,
                                                   const float* __restrict__ ta_proj,
                                                   float* __restrict__ temp_w) {
    __shared__ float rl[Nn_ * Tt_];
    __shared__ float sg[Tt_ * Tt_];
    __shared__ float Eb[Tt_ * Tt_];
    int b = blockIdx.x;
    int tid = threadIdx.x;
    for (int i = tid; i < Nn_ * Tt_; i += 576) rl[i] = rhs_t[b * Nn_ * Tt_ + i];
    __syncthreads();
    int u = tid % Tt_;
    int t = tid / Tt_;
    const float* lp = lhs_t + (b * Tt_ + t) * Nn_;
    float s = 0.f;
    for (int n = 0; n < Nn_; ++n) s += lp[n] * rl[n * Tt_ + u];
    sg[t * Tt_ + u] = sigmoidf_(s + ta_bias[t * Tt_ + u]);
    __syncthreads();
    float e = 0.f;
#pragma unroll
    for (int k = 0; k < Tt_; ++k) e += ta_proj[t * Tt_ + k] * sg[k * Tt_ + u];
    Eb[t * Tt_ + u] = e;
    __syncthreads();
    if (tid < Tt_) {
        int uu = tid;
        float m = -1e30f;
        for (int s2 = 0; s2 < Tt_; ++s2) m = fmaxf(m, Eb[s2 * Tt_ + uu]);
        float sum = 0.f;
        for (int s2 = 0; s2 < Tt_; ++s2) sum += __expf(Eb[s2 * Tt_ + uu] - m);
        float inv = 1.0f / sum;
        for (int s2 = 0; s2 < Tt_; ++s2)
            temp_w[b * Tt_ * Tt_ + s2 * Tt_ + uu] = __expf(Eb[s2 * Tt_ + uu] - m) * inv;
    }
}

__global__ __launch_bounds__(256) void ke_spatial(const float* __restrict__ x,
                                                  const float* __restrict__ tw,
                                                  const float* __restrict__ sa_wa,
                                                  const float* __restrict__ sa_wb,
                                                  const float* __restrict__ sa_wc,
                                                  float* __restrict__ lhs_s,
                                                  float* __restrict__ rhs_s) {
    __shared__ float xl[Ff_ * Tt_];
    __shared__ float twl[Tt_ * Tt_];
    __shared__ float xtl[Ff_ * Tt_];
    __shared__ float tmp2[Ff_];
    int n = blockIdx.x, b = blockIdx.y, tid = threadIdx.x;
    const float* xp = x + ((size_t)(b * Nn_ + n)) * Ff_ * Tt_;
    for (int i = tid; i < Ff_ * Tt_; i += 256) xl[i] = xp[i];
    for (int i = tid; i < Tt_ * Tt_; i += 256) twl[i] = tw[b * Tt_ * Tt_ + i];
    __syncthreads();
    for (int i = tid; i < Ff_ * Tt_; i += 256) {
        int f = i / Tt_, u = i % Tt_;
        float s = 0.f;
#pragma unroll
        for (int t = 0; t < Tt_; ++t) s += xl[f * Tt_ + t] * twl[t * Tt_ + u];
        xtl[i] = s;
    }
    __syncthreads();
    if (tid < Ff_) {
        float s = 0.f;
#pragma unroll
        for (int t = 0; t < Tt_; ++t) s += xtl[tid * Tt_ + t] * sa_wa[t];
        tmp2[tid] = s;
    }
    __syncthreads();
    if (tid < Tt_) {
        float a = 0.f, r = 0.f;
#pragma unroll
        for (int f = 0; f < Ff_; ++f) {
            a += tmp2[f] * sa_wb[f * Tt_ + tid];
            r += sa_wc[f] * xtl[f * Tt_ + tid];
        }
        int o = (b * Nn_ + n) * Tt_ + tid;
        lhs_s[o] = a;
        rhs_s[o] = r;
    }
}

__global__ __launch_bounds__(256) void kg_attn(const float* __restrict__ lhs_s,
                                               const float* __restrict__ rhs_s,
                                               const float* __restrict__ sa_bias,
                                               float* __restrict__ attn) {
    __shared__ float rl[Nn_ * 25];
    __shared__ float ll[16 * Tt_];
    int b = blockIdx.y;
    int n0 = blockIdx.x * 16;
    int tid = threadIdx.x;
    for (int i = tid; i < Nn_ * Tt_; i += 256) {
        int m = i / Tt_, t = i % Tt_;
        rl[m * 25 + t] = rhs_s[b * Nn_ * Tt_ + i];
    }
    for (int i = tid; i < 16 * Tt_; i += 256) ll[i] = lhs_s[b * Nn_ * Tt_ + n0 * Tt_ + i];
    __syncthreads();
    for (int idx = tid; idx < 16 * Nn_; idx += 256) {
        int r = idx >> 9;
        int m = idx & (Nn_ - 1);
        const float* lp = ll + r * Tt_;
        const float* rp = rl + m * 25;
        float s = 0.f;
#pragma unroll
        for (int t = 0; t < Tt_; ++t) s += lp[t] * rp[t];
        int n = n0 + r;
        attn[((size_t)b * Nn_ + n) * Nn_ + m] = sigmoidf_(s + sa_bias[n * Nn_ + m]);
    }
}

// S[b] = proj @ attn[b]   (fp32 tiled; kept fp32: softmax amplifies logit error)
__global__ __launch_bounds__(256) void kh_sgemm(const float* __restrict__ proj,
                                                const float* __restrict__ attn,
                                                float* __restrict__ S) {
    __shared__ float As[16 * 68];
    __shared__ float Bs[16 * 64];
    int b = blockIdx.z;
    int row0 = blockIdx.y * 64, col0 = blockIdx.x * 64;
    int tid = threadIdx.x, tx = tid & 15, ty = tid >> 4;
    const float* Bbase = attn + (size_t)b * Nn_ * Nn_;
    float acc[4][4] = {{0.f}};
    int lr = tid >> 2, lq = tid & 3;
    int bk = tid >> 4, bq = tid & 15;
    for (int k0 = 0; k0 < Nn_; k0 += 16) {
        float4 av = *(const float4*)(proj + (size_t)(row0 + lr) * Nn_ + k0 + lq * 4);
        As[(lq * 4 + 0) * 68 + lr] = av.x;
        As[(lq * 4 + 1) * 68 + lr] = av.y;
        As[(lq * 4 + 2) * 68 + lr] = av.z;
        As[(lq * 4 + 3) * 68 + lr] = av.w;
        float4 bv = *(const float4*)(Bbase + (size_t)(k0 + bk) * Nn_ + col0 + bq * 4);
        *(float4*)(Bs + bk * 64 + bq * 4) = bv;
        __syncthreads();
#pragma unroll
        for (int kk = 0; kk < 16; ++kk) {
            float4 a4 = *(const float4*)(As + kk * 68 + ty * 4);
            float4 b4 = *(const float4*)(Bs + kk * 64 + tx * 4);
            float aa[4] = {a4.x, a4.y, a4.z, a4.w};
            float bbv[4] = {b4.x, b4.y, b4.z, b4.w};
#pragma unroll
            for (int i = 0; i < 4; ++i)
#pragma unroll
                for (int j = 0; j < 4; ++j) acc[i][j] += aa[i] * bbv[j];
        }
        __syncthreads();
    }
    float* Cb = S + (size_t)b * Nn_ * Nn_;
#pragma unroll
    for (int i = 0; i < 4; ++i) {
        float4 v = make_float4(acc[i][0], acc[i][1], acc[i][2], acc[i][3]);
        *(float4*)(Cb + (size_t)(row0 + ty * 4 + i) * Nn_ + col0 + tx * 4) = v;
    }
}

// column softmax over n, 4-way n-split per block
__global__ __launch_bounds__(256) void kj2(float* __restrict__ S) {
    __shared__ float mred[4][64], sred[4][64];
    int b = blockIdx.y;
    int l = threadIdx.x & 63;
    int ng = threadIdx.x >> 6;
    int p = blockIdx.x * 64 + l;
    float* Sp = S + (size_t)b * Nn_ * Nn_ + p;
    float m = -1e30f, s = 0.f;
    for (int n = ng * 128; n < ng * 128 + 128; ++n) {
        float v = Sp[(size_t)n * Nn_];
        float nm = fmaxf(m, v);
        s = s * __expf(m - nm) + __expf(v - nm);
        m = nm;
    }
    mred[ng][l] = m;
    sred[ng][l] = s;
    __syncthreads();
    float M = -1e30f;
#pragma unroll
    for (int g = 0; g < 4; ++g) M = fmaxf(M, mred[g][l]);
    float SS = 0.f;
#pragma unroll
    for (int g = 0; g < 4; ++g) SS += sred[g][l] * __expf(mred[g][l] - M);
    float inv = 1.0f / SS;
    for (int n = ng * 128; n < ng * 128 + 128; ++n) {
        float v = Sp[(size_t)n * Nn_];
        Sp[(size_t)n * Nn_] = __expf(v - M) * inv;
    }
}

// XT[b][q][m] bf16 = x[b][m][q]  (tile transpose + cvt)
__global__ __launch_bounds__(256) void kxT(const float* __restrict__ x,
                                           unsigned short* __restrict__ XT) {
    __shared__ float tl[64][65];
    int q0 = blockIdx.x * 64, m0 = blockIdx.y * 64, b = blockIdx.z;
    int tid = threadIdx.x, j = tid & 63, i4 = tid >> 6;
#pragma unroll
    for (int r = 0; r < 16; ++r) {
        int i = i4 + r * 4;
        tl[i][j] = x[((size_t)(b * Nn_ + m0 + i)) * 768 + q0 + j];
    }
    __syncthreads();
#pragma unroll
    for (int r = 0; r < 16; ++r) {
        int qq = i4 + r * 4;
        XT[((size_t)b * 768 + q0 + qq) * Nn_ + m0 + j] = f2bf(tl[j][qq]);
    }
}

// AT[b][p][m] bf16 = cheb[k][m][p] * spat[b][m][p]  (tile transpose + product + cvt)
__global__ __launch_bounds__(256) void kaT(const float* __restrict__ cheb,
                                           const float* __restrict__ spat,
                                           unsigned short* __restrict__ AT, int k) {
    __shared__ float tl[64][65];
    int p0 = blockIdx.x * 64, m0 = blockIdx.y * 64, b = blockIdx.z;
    int tid = threadIdx.x, j = tid & 63, i4 = tid >> 6;
#pragma unroll
    for (int r = 0; r < 16; ++r) {
        int i = i4 + r * 4;
        size_t off = (size_t)(m0 + i) * Nn_ + p0 + j;
        tl[i][j] = cheb[(size_t)k * Nn_ * Nn_ + off] * spat[(size_t)b * Nn_ * Nn_ + off];
    }
    __syncthreads();
#pragma unroll
    for (int r = 0; r < 16; ++r) {
        int pp = i4 + r * 4;
        AT[((size_t)b * Nn_ + p0 + pp) * Nn_ + m0 + j] = f2bf(tl[j][pp]);
    }
}

// H[b][p][q] bf16 = sum_m AT[b][p][m] * XT[b][q][m]  — bf16 MFMA, 128x128 tile
__global__ __launch_bounds__(256) void hgemm_mfma(const unsigned short* __restrict__ AT,
                                                  const unsigned short* __restrict__ XT,
                                                  unsigned short* __restrict__ H) {
    __shared__ unsigned short As[512 * 8];   // 512 chunks x 16B = 8KB
    __shared__ unsigned short Bs[512 * 8];
    int b = blockIdx.z;
    int p0 = blockIdx.y * 128;
    int q0 = blockIdx.x * 128;
    int tid = threadIdx.x;
    int wid = tid >> 6, lane = tid & 63;
    int l15 = lane & 15, l4 = lane >> 4;
    int wm = (wid & 1) * 64, wn = (wid >> 1) * 64;
    const unsigned short* Ab = AT + (size_t)b * Nn_ * Nn_;
    const unsigned short* Bb = XT + (size_t)b * 768 * Nn_;

    // staging chunk positions (swizzled): position c -> row=c>>2, kc=(c&3)^((row>>1)&3)
    int cp0 = wid * 128 + lane;
    int cp1 = cp0 + 64;
    int rA0 = cp0 >> 2, kA0 = (cp0 & 3) ^ ((rA0 >> 1) & 3);
    int rA1 = cp1 >> 2, kA1 = (cp1 & 3) ^ ((rA1 >> 1) & 3);
    const unsigned short* gA0 = Ab + (size_t)(p0 + rA0) * Nn_ + kA0 * 8;
    const unsigned short* gA1 = Ab + (size_t)(p0 + rA1) * Nn_ + kA1 * 8;
    const unsigned short* gB0 = Bb + (size_t)(q0 + rA0) * Nn_ + kA0 * 8;
    const unsigned short* gB1 = Bb + (size_t)(q0 + rA1) * Nn_ + kA1 * 8;
    unsigned short* lA0 = As + (size_t)(wid * 128) * 8;
    unsigned short* lA1 = As + (size_t)(wid * 128 + 64) * 8;
    unsigned short* lB0 = Bs + (size_t)(wid * 128) * 8;
    unsigned short* lB1 = Bs + (size_t)(wid * 128 + 64) * 8;

    // fragment read chunk indices
    int ca[4], cb[4];
#pragma unroll
    for (int i = 0; i < 4; ++i) {
        int row = wm + i * 16 + l15;
        ca[i] = row * 4 + (l4 ^ ((row >> 1) & 3));
        row = wn + i * 16 + l15;
        cb[i] = row * 4 + (l4 ^ ((row >> 1) & 3));
    }

    f32x4 acc[4][4];
#pragma unroll
    for (int i = 0; i < 4; ++i)
#pragma unroll
        for (int j = 0; j < 4; ++j) acc[i][j] = (f32x4){0.f, 0.f, 0.f, 0.f};

    for (int ks = 0; ks < 16; ++ks) {
        __syncthreads();
        async16(gA0 + ks * 32, lA0);
        async16(gA1 + ks * 32, lA1);
        async16(gB0 + ks * 32, lB0);
        async16(gB1 + ks * 32, lB1);
        __syncthreads();
        bf16x8 af[4], bfv[4];
#pragma unroll
        for (int i = 0; i < 4; ++i) af[i] = *(const bf16x8*)(As + (size_t)ca[i] * 8);
#pragma unroll
        for (int j = 0; j < 4; ++j) bfv[j] = *(const bf16x8*)(Bs + (size_t)cb[j] * 8);
#pragma unroll
        for (int i = 0; i < 4; ++i)
#pragma unroll
            for (int j = 0; j < 4; ++j)
                acc[i][j] = __builtin_amdgcn_mfma_f32_16x16x32_bf16(af[i], bfv[j], acc[i][j], 0, 0, 0);
    }

    unsigned short* Hb = H + (size_t)b * Nn_ * 768;
#pragma unroll
    for (int i = 0; i < 4; ++i)
#pragma unroll
        for (int j = 0; j < 4; ++j) {
            int p = p0 + wm + i * 16 + l4 * 4;
            int q = q0 + wn + j * 16 + l15;
#pragma unroll
            for (int r = 0; r < 4; ++r)
                Hb[(size_t)(p + r) * 768 + q] = f2bf(acc[i][j][r]);
        }
}

// y[b,n,o,t] = relu( sum_k sum_f H_k[b,n,f*T+t] * w_cheb[k,f,o] )
__global__ __launch_bounds__(256) void kacc3(const unsigned short* __restrict__ H,
                                             const float* __restrict__ wch,
                                             float* __restrict__ y) {
    __shared__ float wl[3 * Ff_ * GC_];   // 6144 f = 24KB
    __shared__ float hlf[3 * Ff_ * Tt_];  // 2304 f = 9.2KB
    int b = blockIdx.y, ng = blockIdx.x, tid = threadIdx.x;
    for (int i = tid; i < 3 * Ff_ * GC_; i += 256) wl[i] = wch[i];
    for (int it = 0; it < 8; ++it) {
        int n = ng * 8 + it;
        __syncthreads();
        for (int i = tid; i < 2304; i += 256) {
            int k = i / 768, i2 = i - k * 768;
            hlf[i] = bf2f(H[(size_t)k * 12582912 + ((size_t)(b * Nn_ + n)) * 768 + i2]);
        }
        __syncthreads();
        float* yp = y + ((size_t)(b * Nn_ + n)) * GC_ * Tt_;
#pragma unroll
        for (int s = 0; s < 6; ++s) {
            int idx = s * 256 + tid;
            int o = idx / Tt_, t = idx - o * Tt_;
            float acc = 0.f;
#pragma unroll
            for (int k = 0; k < 3; ++k)
#pragma unroll
                for (int f = 0; f < Ff_; ++f)
                    acc += hlf[k * 768 + f * Tt_ + t] * wl[(k * Ff_ + f) * GC_ + o];
            yp[idx] = acc > 0.f ? acc : 0.f;
        }
    }
}

// transpose time_w: twT[(g*3+j)*64 + c] = time_w[c*192 + g*3+j]
__global__ void kwT(const float* __restrict__ tw, float* __restrict__ twT) {
    int i = blockIdx.x * 256 + threadIdx.x;   // 12288
    int c = i & 63, r = i >> 6;
    twT[i] = tw[c * 192 + r];
}

// in-place 1x3 conv over t; weights streamed from global (L2-resident 48KB)
__global__ __launch_bounds__(256) void kk1b(float* __restrict__ y,
                                            const float* __restrict__ twT) {
    __shared__ float gl[4][GC_ * 26];   // 26.6KB
    int b = blockIdx.y, nb = blockIdx.x * 16;
    int tid = threadIdx.x, sub = tid >> 6, c = tid & 63;
    gl[sub][c * 26] = 0.f;
    gl[sub][c * 26 + 25] = 0.f;
    __syncthreads();
    for (int it = 0; it < 4; ++it) {
        int n = nb + it * 4 + sub;
        float* yp = y + ((size_t)(b * Nn_ + n)) * GC_ * Tt_;
        for (int i = c; i < GC_ * Tt_; i += 64) {
            int g = i / Tt_, t = i - g * Tt_;
            gl[sub][g * 26 + t + 1] = yp[i];
        }
        __syncthreads();
        float acc[Tt_];
#pragma unroll
        for (int t = 0; t < Tt_; ++t) acc[t] = 0.f;
        for (int g = 0; g < GC_; ++g) {
            float w0 = twT[(g * 3 + 0) * 64 + c];
            float w1 = twT[(g * 3 + 1) * 64 + c];
            float w2 = twT[(g * 3 + 2) * 64 + c];
            const float* gp = &gl[sub][g * 26];
            float a = gp[0], bb = gp[1];
#pragma unroll
            for (int t = 0; t < Tt_; ++t) {
                float cc2 = gp[t + 2];
                acc[t] += w0 * a + w1 * bb + w2 * cc2;
                a = bb;
                bb = cc2;
            }
        }
        __syncthreads();
#pragma unroll
        for (int t = 0; t < Tt_; ++t) yp[c * Tt_ + t] = acc[t];
        __syncthreads();
    }
}

// skip(1x1) + biases + relu + layernorm(over c) + transposed store
__global__ __launch_bounds__(256) void kk2_ln(const float* __restrict__ pre,
                                              const float* __restrict__ x,
                                              const float* __restrict__ skip_w,
                                              const float* __restrict__ time_b,
                                              const float* __restrict__ skip_b,
                                              const float* __restrict__ ln_g,
                                              const float* __restrict__ ln_b,
                                              float* __restrict__ out) {
    __shared__ float pl[TC_ * Tt_];
    __shared__ float xl[Ff_ * Tt_];
    __shared__ float swl[Ff_ * TC_];
    __shared__ float bias0[TC_], lg[TC_], lb[TC_];
    int n = blockIdx.x, b = blockIdx.y, tid = threadIdx.x;
    const float* pp = pre + ((size_t)(b * Nn_ + n)) * TC_ * Tt_;
    for (int i = tid; i < TC_ * Tt_; i += 256) pl[i] = pp[i];
    const float* xp = x + ((size_t)(b * Nn_ + n)) * Ff_ * Tt_;
    for (int i = tid; i < Ff_ * Tt_; i += 256) xl[i] = xp[i];
    for (int i = tid; i < Ff_ * TC_; i += 256) {
        int f = i >> 6, cc = i & 63;
        swl[i] = skip_w[cc * Ff_ + f];
    }
    if (tid < TC_) {
        bias0[tid] = time_b[tid] + skip_b[tid];
        lg[tid] = ln_g[tid];
        lb[tid] = ln_b[tid];
    }
    __syncthreads();
    int c = tid & 63, tg = tid >> 6;
    float sv[6];
#pragma unroll
    for (int ti = 0; ti < 6; ++ti) sv[ti] = pl[c * Tt_ + (tg + ti * 4)] + bias0[c];
    for (int f = 0; f < Ff_; ++f) {
        float w = swl[f * TC_ + c];
#pragma unroll
        for (int ti = 0; ti < 6; ++ti) sv[ti] += w * xl[f * Tt_ + tg + ti * 4];
    }
#pragma unroll
    for (int ti = 0; ti < 6; ++ti) {
        float v = sv[ti] > 0.f ? sv[ti] : 0.f;
        float sum = v, sq = v * v;
#pragma unroll
        for (int off = 32; off > 0; off >>= 1) {
            sum += __shfl_xor(sum, off, 64);
            sq += __shfl_xor(sq, off, 64);
        }
        float mu = sum * (1.0f / 64.0f);
        float var = sq * (1.0f / 64.0f) - mu * mu;
        float r = rsqrtf(var + 1e-5f);
        int t = tg + ti * 4;
        out[(((size_t)(b * Nn_ + n)) * TC_ + c) * Tt_ + t] = (v - mu) * r * lg[c] + lb[c];
    }
}

extern "C" void kernel_launch(void* const* d_in, const int* in_sizes, int n_in,
                              void* d_out, int out_size, void* d_ws, size_t ws_size,
                              hipStream_t stream) {
    const float* x       = (const float*)d_in[0];
    const float* cheb    = (const float*)d_in[1];
    const float* w_cheb  = (const float*)d_in[2];
    const float* sa_wa   = (const float*)d_in[3];
    const float* sa_wb   = (const float*)d_in[4];
    const float* sa_wc   = (const float*)d_in[5];
    const float* sa_bias = (const float*)d_in[6];
    const float* sa_proj = (const float*)d_in[7];
    const float* ta_w1   = (const float*)d_in[8];
    const float* ta_w2   = (const float*)d_in[9];
    const float* ta_w3   = (const float*)d_in[10];
    const float* ta_bias = (const float*)d_in[11];
    const float* ta_proj = (const float*)d_in[12];
    const float* time_w  = (const float*)d_in[13];
    const float* time_b  = (const float*)d_in[14];
    const float* skip_w  = (const float*)d_in[15];
    const float* skip_b  = (const float*)d_in[16];
    const float* ln_g    = (const float*)d_in[17];
    const float* ln_b    = (const float*)d_in[18];
    float* out = (float*)d_out;

    // ---- workspace layout (191 MB total; ybuf aliases dead attn/Sbuf/XT/AT) ----
    float* ws    = (float*)d_ws;
    float* tmp   = ws;                      // 24576 f
    float* lhs_t = tmp + 24576;             // 393216 f
    float* rhs_t = lhs_t + 393216;          // 393216 f
    float* tw    = rhs_t + 393216;          // 18432 f
    float* lhs_s = tw + 18432;              // 393216 f
    float* rhs_s = lhs_s + 393216;          // 393216 f
    float* twT   = rhs_s + 393216;          // 12288 f
    float* attn  = twT + 12288;             // 8388608 f   (regionA base)
    float* Sbuf  = attn + 8388608;          // 8388608 f
    unsigned short* XT = (unsigned short*)(Sbuf + 8388608);   // 12582912 us
    unsigned short* AT = XT + 12582912;                       // 8388608 us
    float* ybuf  = attn;                    // alias: 100.7MB <= 109.1MB region
    unsigned short* hbuf = (unsigned short*)((char*)attn + 109051904);  // 3 x 12582912 us

    kwT<<<48, 256, 0, stream>>>(time_w, twT);
    kxT<<<dim3(12, 8, 32), 256, 0, stream>>>(x, XT);
    ka_tmp<<<96, 256, 0, stream>>>(x, ta_w1, tmp);
    kb_rhs<<<1536, 256, 0, stream>>>(x, ta_w3, rhs_t);
    kc_lhs<<<1536, 256, 0, stream>>>(tmp, ta_w2, lhs_t);
    kd_temporal<<<32, 576, 0, stream>>>(lhs_t, rhs_t, ta_bias, ta_proj, tw);
    ke_spatial<<<dim3(512, 32), 256, 0, stream>>>(x, tw, sa_wa, sa_wb, sa_wc, lhs_s, rhs_s);
    kg_attn<<<dim3(32, 32), 256, 0, stream>>>(lhs_s, rhs_s, sa_bias, attn);
    kh_sgemm<<<dim3(8, 8, 32), 256, 0, stream>>>(sa_proj, attn, Sbuf);
    kj2<<<dim3(8, 32), 256, 0, stream>>>(Sbuf);
    for (int k = 0; k < 3; ++k) {
        kaT<<<dim3(8, 8, 32), 256, 0, stream>>>(cheb, Sbuf, AT, k);
        hgemm_mfma<<<dim3(6, 4, 32), 256, 0, stream>>>(AT, XT, hbuf + (size_t)k * 12582912);
    }
    kacc3<<<dim3(64, 32), 256, 0, stream>>>(hbuf, w_cheb, ybuf);
    kk1b<<<dim3(32, 32), 256, 0, stream>>>(ybuf, twT);
    kk2_ln<<<dim3(512, 32), 256, 0, stream>>>(ybuf, x, skip_w, time_b, skip_b, ln_g, ln_b, out);
}

// Round 3
// 671.971 us; speedup vs baseline: 2.6122x; 1.9504x over previous
//
#include <hip/hip_runtime.h>
#include <math.h>

#define Bb_ 32
#define Nn_ 512
#define Ff_ 32
#define Tt_ 24
#define GC_ 64
#define TC_ 64

typedef __attribute__((ext_vector_type(8))) short bf16x8;
typedef __attribute__((ext_vector_type(4))) float f32x4;
typedef __attribute__((ext_vector_type(8))) unsigned short u16x8;
typedef __attribute__((ext_vector_type(4))) unsigned short u16x4;

__device__ __forceinline__ float sigmoidf_(float v) { return 1.0f / (1.0f + __expf(-v)); }

__device__ __forceinline__ unsigned short f2bf(float f) {
    unsigned u = __float_as_uint(f);
    u = (u + 0x7fffu + ((u >> 16) & 1u)) >> 16;
    return (unsigned short)u;
}

__device__ __forceinline__ void async16(const void* g, void* l) {
    __builtin_amdgcn_global_load_lds((const __attribute__((address_space(1))) unsigned int*)g,
                                     (__attribute__((address_space(3))) unsigned int*)l,
                                     16, 0, 0);
}

// ---------------- temporal attention pieces ----------------
__global__ void ka_tmp(const float* __restrict__ x, const float* __restrict__ w1,
                       float* __restrict__ tmp) {
    int tid = blockIdx.x * blockDim.x + threadIdx.x;
    int t = tid % Tt_;
    int f = (tid / Tt_) % Ff_;
    int b = tid / (Tt_ * Ff_);
    const float* xp = x + ((size_t)b * Nn_ * Ff_ + f) * Tt_ + t;
    float s = 0.f;
    for (int n = 0; n < Nn_; ++n) s += xp[(size_t)n * Ff_ * Tt_] * w1[n];
    tmp[(b * Tt_ + t) * Ff_ + f] = s;
}

__global__ void kb_rhs(const float* __restrict__ x, const float* __restrict__ w3,
                       float* __restrict__ rhs_t) {
    int tid = blockIdx.x * blockDim.x + threadIdx.x;
    int t = tid % Tt_;
    int n = (tid / Tt_) % Nn_;
    int b = tid / (Tt_ * Nn_);
    const float* xp = x + (((size_t)b * Nn_ + n) * Ff_) * Tt_ + t;
    float s = 0.f;
#pragma unroll
    for (int f = 0; f < Ff_; ++f) s += w3[f] * xp[f * Tt_];
    rhs_t[(b * Nn_ + n) * Tt_ + t] = s;
}

__global__ void kc_lhs(const float* __restrict__ tmp, const float* __restrict__ w2,
                       float* __restrict__ lhs_t) {
    int tid = blockIdx.x * blockDim.x + threadIdx.x;
    int n = tid % Nn_;
    int t = (tid / Nn_) % Tt_;
    int b = tid / (Nn_ * Tt_);
    const float* tp = tmp + (b * Tt_ + t) * Ff_;
    float s = 0.f;
#pragma unroll
    for (int f = 0; f < Ff_; ++f) s += tp[f] * w2[f * Nn_ + n];
    lhs_t[(b * Tt_ + t) * Nn_ + n] = s;
}

__global__ __launch_bounds__(576) void kd_temporal(const float* __restrict__ lhs_t,
                                                   const float* __restrict__ rhs_t,
                                                   const float* __restrict__ ta_bias,
                                                   const float* __restrict__ ta_proj,
                                                   float* __restrict__ temp_w) {
    __shared__ float rl[Nn_ * Tt_];
    __shared__ float sg[Tt_ * Tt_];
    __shared__ float Eb[Tt_ * Tt_];
    int b = blockIdx.x;
    int tid = threadIdx.x;
    for (int i = tid; i < Nn_ * Tt_; i += 576) rl[i] = rhs_t[b * Nn_ * Tt_ + i];
    __syncthreads();
    int u = tid % Tt_;
    int t = tid / Tt_;
    const float* lp = lhs_t + (b * Tt_ + t) * Nn_;
    float s = 0.f;
    for (int n = 0; n < Nn_; ++n) s += lp[n] * rl[n * Tt_ + u];
    sg[t * Tt_ + u] = sigmoidf_(s + ta_bias[t * Tt_ + u]);
    __syncthreads();
    float e = 0.f;
#pragma unroll
    for (int k = 0; k < Tt_; ++k) e += ta_proj[t * Tt_ + k] * sg[k * Tt_ + u];
    Eb[t * Tt_ + u] = e;
    __syncthreads();
    if (tid < Tt_) {
        int uu = tid;
        float m = -1e30f;
        for (int s2 = 0; s2 < Tt_; ++s2) m = fmaxf(m, Eb[s2 * Tt_ + uu]);
        float sum = 0.f;
        for (int s2 = 0; s2 < Tt_; ++s2) sum += __expf(Eb[s2 * Tt_ + uu] - m);
        float inv = 1.0f / sum;
        for (int s2 = 0; s2 < Tt_; ++s2)
            temp_w[b * Tt_ * Tt_ + s2 * Tt_ + uu] = __expf(Eb[s2 * Tt_ + uu] - m) * inv;
    }
}

__global__ __launch_bounds__(256) void ke_spatial(const float* __restrict__ x,
                                                  const float* __restrict__ tw,
                                                  const float* __restrict__ sa_wa,
                                                  const float* __restrict__ sa_wb,
                                                  const float* __restrict__ sa_wc,
                                                  float* __restrict__ lhs_s,
                                                  float* __restrict__ rhs_s) {
    __shared__ float xl[Ff_ * Tt_];
    __shared__ float twl[Tt_ * Tt_];
    __shared__ float xtl[Ff_ * Tt_];
    __shared__ float tmp2[Ff_];
    int n = blockIdx.x, b = blockIdx.y, tid = threadIdx.x;
    const float* xp = x + ((size_t)(b * Nn_ + n)) * Ff_ * Tt_;
    for (int i = tid; i < Ff_ * Tt_; i += 256) xl[i] = xp[i];
    for (int i = tid; i < Tt_ * Tt_; i += 256) twl[i] = tw[b * Tt_ * Tt_ + i];
    __syncthreads();
    for (int i = tid; i < Ff_ * Tt_; i += 256) {
        int f = i / Tt_, u = i % Tt_;
        float s = 0.f;
#pragma unroll
        for (int t = 0; t < Tt_; ++t) s += xl[f * Tt_ + t] * twl[t * Tt_ + u];
        xtl[i] = s;
    }
    __syncthreads();
    if (tid < Ff_) {
        float s = 0.f;
#pragma unroll
        for (int t = 0; t < Tt_; ++t) s += xtl[tid * Tt_ + t] * sa_wa[t];
        tmp2[tid] = s;
    }
    __syncthreads();
    if (tid < Tt_) {
        float a = 0.f, r = 0.f;
#pragma unroll
        for (int f = 0; f < Ff_; ++f) {
            a += tmp2[f] * sa_wb[f * Tt_ + tid];
            r += sa_wc[f] * xtl[f * Tt_ + tid];
        }
        int o = (b * Nn_ + n) * Tt_ + tid;
        lhs_s[o] = a;
        rhs_s[o] = r;
    }
}

__global__ __launch_bounds__(256) void kg_attn(const float* __restrict__ lhs_s,
                                               const float* __restrict__ rhs_s,
                                               const float* __restrict__ sa_bias,
                                               float* __restrict__ attn) {
    __shared__ float rl[Nn_ * 25];
    __shared__ float ll[16 * Tt_];
    int b = blockIdx.y;
    int n0 = blockIdx.x * 16;
    int tid = threadIdx.x;
    for (int i = tid; i < Nn_ * Tt_; i += 256) {
        int m = i / Tt_, t = i % Tt_;
        rl[m * 25 + t] = rhs_s[b * Nn_ * Tt_ + i];
    }
    for (int i = tid; i < 16 * Tt_; i += 256) ll[i] = lhs_s[b * Nn_ * Tt_ + n0 * Tt_ + i];
    __syncthreads();
    for (int idx = tid; idx < 16 * Nn_; idx += 256) {
        int r = idx >> 9;
        int m = idx & (Nn_ - 1);
        const float* lp = ll + r * Tt_;
        const float* rp = rl + m * 25;
        float s = 0.f;
#pragma unroll
        for (int t = 0; t < Tt_; ++t) s += lp[t] * rp[t];
        int n = n0 + r;
        attn[((size_t)b * Nn_ + n) * Nn_ + m] = sigmoidf_(s + sa_bias[n * Nn_ + m]);
    }
}

// S[b] = proj @ attn[b]   (fp32 tiled; kept fp32: softmax amplifies logit error)
__global__ __launch_bounds__(256) void kh_sgemm(const float* __restrict__ proj,
                                                const float* __restrict__ attn,
                                                float* __restrict__ S) {
    __shared__ float As[16 * 68];
    __shared__ float Bs[16 * 64];
    int b = blockIdx.z;
    int row0 = blockIdx.y * 64, col0 = blockIdx.x * 64;
    int tid = threadIdx.x, tx = tid & 15, ty = tid >> 4;
    const float* Bbase = attn + (size_t)b * Nn_ * Nn_;
    float acc[4][4] = {{0.f}};
    int lr = tid >> 2, lq = tid & 3;
    int bk = tid >> 4, bq = tid & 15;
    for (int k0 = 0; k0 < Nn_; k0 += 16) {
        float4 av = *(const float4*)(proj + (size_t)(row0 + lr) * Nn_ + k0 + lq * 4);
        As[(lq * 4 + 0) * 68 + lr] = av.x;
        As[(lq * 4 + 1) * 68 + lr] = av.y;
        As[(lq * 4 + 2) * 68 + lr] = av.z;
        As[(lq * 4 + 3) * 68 + lr] = av.w;
        float4 bv = *(const float4*)(Bbase + (size_t)(k0 + bk) * Nn_ + col0 + bq * 4);
        *(float4*)(Bs + bk * 64 + bq * 4) = bv;
        __syncthreads();
#pragma unroll
        for (int kk = 0; kk < 16; ++kk) {
            float4 a4 = *(const float4*)(As + kk * 68 + ty * 4);
            float4 b4 = *(const float4*)(Bs + kk * 64 + tx * 4);
            float aa[4] = {a4.x, a4.y, a4.z, a4.w};
            float bbv[4] = {b4.x, b4.y, b4.z, b4.w};
#pragma unroll
            for (int i = 0; i < 4; ++i)
#pragma unroll
                for (int j = 0; j < 4; ++j) acc[i][j] += aa[i] * bbv[j];
        }
        __syncthreads();
    }
    float* Cb = S + (size_t)b * Nn_ * Nn_;
#pragma unroll
    for (int i = 0; i < 4; ++i) {
        float4 v = make_float4(acc[i][0], acc[i][1], acc[i][2], acc[i][3]);
        *(float4*)(Cb + (size_t)(row0 + ty * 4 + i) * Nn_ + col0 + tx * 4) = v;
    }
}

// column softmax over n, 4-way n-split per block
__global__ __launch_bounds__(256) void kj2(float* __restrict__ S) {
    __shared__ float mred[4][64], sred[4][64];
    int b = blockIdx.y;
    int l = threadIdx.x & 63;
    int ng = threadIdx.x >> 6;
    int p = blockIdx.x * 64 + l;
    float* Sp = S + (size_t)b * Nn_ * Nn_ + p;
    float m = -1e30f, s = 0.f;
    for (int n = ng * 128; n < ng * 128 + 128; ++n) {
        float v = Sp[(size_t)n * Nn_];
        float nm = fmaxf(m, v);
        s = s * __expf(m - nm) + __expf(v - nm);
        m = nm;
    }
    mred[ng][l] = m;
    sred[ng][l] = s;
    __syncthreads();
    float M = -1e30f;
#pragma unroll
    for (int g = 0; g < 4; ++g) M = fmaxf(M, mred[g][l]);
    float SS = 0.f;
#pragma unroll
    for (int g = 0; g < 4; ++g) SS += sred[g][l] * __expf(mred[g][l] - M);
    float inv = 1.0f / SS;
    for (int n = ng * 128; n < ng * 128 + 128; ++n) {
        float v = Sp[(size_t)n * Nn_];
        Sp[(size_t)n * Nn_] = __expf(v - M) * inv;
    }
}

// XT[b][q][m] bf16 = x[b][m][q]
__global__ __launch_bounds__(256) void kxT(const float* __restrict__ x,
                                           unsigned short* __restrict__ XT) {
    __shared__ float tl[64][65];
    int q0 = blockIdx.x * 64, m0 = blockIdx.y * 64, b = blockIdx.z;
    int tid = threadIdx.x, j = tid & 63, i4 = tid >> 6;
#pragma unroll
    for (int r = 0; r < 16; ++r) {
        int i = i4 + r * 4;
        tl[i][j] = x[((size_t)(b * Nn_ + m0 + i)) * 768 + q0 + j];
    }
    __syncthreads();
#pragma unroll
    for (int r = 0; r < 16; ++r) {
        int qq = i4 + r * 4;
        XT[((size_t)b * 768 + q0 + qq) * Nn_ + m0 + j] = f2bf(tl[j][qq]);
    }
}

// AT[b][p][m] bf16 = cheb[k][m][p] * spat[b][m][p]
__global__ __launch_bounds__(256) void kaT(const float* __restrict__ cheb,
                                           const float* __restrict__ spat,
                                           unsigned short* __restrict__ AT, int k) {
    __shared__ float tl[64][65];
    int p0 = blockIdx.x * 64, m0 = blockIdx.y * 64, b = blockIdx.z;
    int tid = threadIdx.x, j = tid & 63, i4 = tid >> 6;
#pragma unroll
    for (int r = 0; r < 16; ++r) {
        int i = i4 + r * 4;
        size_t off = (size_t)(m0 + i) * Nn_ + p0 + j;
        tl[i][j] = cheb[(size_t)k * Nn_ * Nn_ + off] * spat[(size_t)b * Nn_ * Nn_ + off];
    }
    __syncthreads();
#pragma unroll
    for (int r = 0; r < 16; ++r) {
        int pp = i4 + r * 4;
        AT[((size_t)b * Nn_ + p0 + pp) * Nn_ + m0 + j] = f2bf(tl[j][pp]);
    }
}

// H[b][p][q] bf16 = sum_m AT[b][p][m] * XT[b][q][m]  — bf16 MFMA, 128x128 tile
__global__ __launch_bounds__(256) void hgemm_mfma(const unsigned short* __restrict__ AT,
                                                  const unsigned short* __restrict__ XT,
                                                  unsigned short* __restrict__ H) {
    __shared__ unsigned short As[512 * 8];
    __shared__ unsigned short Bs[512 * 8];
    int b = blockIdx.z;
    int p0 = blockIdx.y * 128;
    int q0 = blockIdx.x * 128;
    int tid = threadIdx.x;
    int wid = tid >> 6, lane = tid & 63;
    int l15 = lane & 15, l4 = lane >> 4;
    int wm = (wid & 1) * 64, wn = (wid >> 1) * 64;
    const unsigned short* Ab = AT + (size_t)b * Nn_ * Nn_;
    const unsigned short* Bb = XT + (size_t)b * 768 * Nn_;

    int cp0 = wid * 128 + lane;
    int cp1 = cp0 + 64;
    int rA0 = cp0 >> 2, kA0 = (cp0 & 3) ^ ((rA0 >> 1) & 3);
    int rA1 = cp1 >> 2, kA1 = (cp1 & 3) ^ ((rA1 >> 1) & 3);
    const unsigned short* gA0 = Ab + (size_t)(p0 + rA0) * Nn_ + kA0 * 8;
    const unsigned short* gA1 = Ab + (size_t)(p0 + rA1) * Nn_ + kA1 * 8;
    const unsigned short* gB0 = Bb + (size_t)(q0 + rA0) * Nn_ + kA0 * 8;
    const unsigned short* gB1 = Bb + (size_t)(q0 + rA1) * Nn_ + kA1 * 8;
    unsigned short* lA0 = As + (size_t)(wid * 128) * 8;
    unsigned short* lA1 = As + (size_t)(wid * 128 + 64) * 8;
    unsigned short* lB0 = Bs + (size_t)(wid * 128) * 8;
    unsigned short* lB1 = Bs + (size_t)(wid * 128 + 64) * 8;

    int ca[4], cb[4];
#pragma unroll
    for (int i = 0; i < 4; ++i) {
        int row = wm + i * 16 + l15;
        ca[i] = row * 4 + (l4 ^ ((row >> 1) & 3));
        row = wn + i * 16 + l15;
        cb[i] = row * 4 + (l4 ^ ((row >> 1) & 3));
    }

    f32x4 acc[4][4];
#pragma unroll
    for (int i = 0; i < 4; ++i)
#pragma unroll
        for (int j = 0; j < 4; ++j) acc[i][j] = (f32x4){0.f, 0.f, 0.f, 0.f};

    for (int ks = 0; ks < 16; ++ks) {
        __syncthreads();
        async16(gA0 + ks * 32, lA0);
        async16(gA1 + ks * 32, lA1);
        async16(gB0 + ks * 32, lB0);
        async16(gB1 + ks * 32, lB1);
        __syncthreads();
        bf16x8 af[4], bfv[4];
#pragma unroll
        for (int i = 0; i < 4; ++i) af[i] = *(const bf16x8*)(As + (size_t)ca[i] * 8);
#pragma unroll
        for (int j = 0; j < 4; ++j) bfv[j] = *(const bf16x8*)(Bs + (size_t)cb[j] * 8);
#pragma unroll
        for (int i = 0; i < 4; ++i)
#pragma unroll
            for (int j = 0; j < 4; ++j)
                acc[i][j] = __builtin_amdgcn_mfma_f32_16x16x32_bf16(af[i], bfv[j], acc[i][j], 0, 0, 0);
    }

    unsigned short* Hb = H + (size_t)b * Nn_ * 768;
#pragma unroll
    for (int i = 0; i < 4; ++i)
#pragma unroll
        for (int j = 0; j < 4; ++j) {
            int p = p0 + wm + i * 16 + l4 * 4;
            int q = q0 + wn + j * 16 + l15;
#pragma unroll
            for (int r = 0; r < 4; ++r)
                Hb[(size_t)(p + r) * 768 + q] = f2bf(acc[i][j][r]);
        }
}

// prep: WA[r][kf] bf16 (kf<96: w_cheb[kf][r]; kf>=96: skip_w[r][kf-96])
//       WC[(j*64+c)][g] bf16 = time_w[c][g][j]
__global__ void kprep(const float* __restrict__ wch, const float* __restrict__ skw,
                      const float* __restrict__ tw,
                      unsigned short* __restrict__ WA, unsigned short* __restrict__ WC) {
    int tid = threadIdx.x;
    for (int i = tid; i < 64 * 128; i += 256) {
        int r = i >> 7, kf = i & 127;
        float v = (kf < 96) ? wch[kf * 64 + r] : skw[r * 32 + (kf - 96)];
        WA[i] = f2bf(v);
    }
    for (int i = tid; i < 192 * 64; i += 256) {
        int j = i / 4096, c = (i >> 6) & 63, g = i & 63;
        WC[i] = f2bf(tw[c * 192 + g * 3 + j]);
    }
}

// -------- fused tail: gcn=relu(H·W), 1x3 conv (3 shifted GEMMs), skip, bias,
// relu, layernorm(c), transposed coalesced store. One block = 1 b x 4 n. -----
#define HS_ 12582912
#define HLP_ 136   // Hl row stride (bf16), K=128+8
#define GLP_ 72    // Gl row stride (bf16), 64+8
#define TLP_ 68    // Tl row stride (f32), 64+4
__global__ __launch_bounds__(256) void ktail(const unsigned short* __restrict__ H,
                                             const float* __restrict__ x,
                                             const unsigned short* __restrict__ WA,
                                             const unsigned short* __restrict__ WC,
                                             const float* __restrict__ time_b,
                                             const float* __restrict__ skip_b,
                                             const float* __restrict__ ln_g,
                                             const float* __restrict__ ln_b,
                                             float* __restrict__ out) {
    __shared__ __align__(16) char pool_[96 * HLP_ * 2];          // Hl (bf16) then Tl (f32)
    __shared__ __align__(16) unsigned short Gl[104 * GLP_];      // 4n x 26 rows (zero borders)
    __shared__ float biasS[64], lgS[64], lbS[64];
    __shared__ float muS[96], rsS[96];
    unsigned short* Hl = (unsigned short*)pool_;
    float* Tl = (float*)pool_;

    int b = blockIdx.y;
    int n0 = blockIdx.x * 4;
    size_t bn0 = (size_t)b * Nn_ + n0;
    int tid = threadIdx.x;
    int w = tid >> 6, lane = tid & 63, l15 = lane & 15, l4 = lane >> 4;

    // A-operand fragments from global (L2-hot, identical across blocks)
    bf16x8 af[4], cf[3][2];
#pragma unroll
    for (int q = 0; q < 4; ++q)
        af[q] = *(const bf16x8*)(WA + (size_t)(16 * w + l15) * 128 + q * 32 + l4 * 8);
#pragma unroll
    for (int j = 0; j < 3; ++j)
#pragma unroll
        for (int kc = 0; kc < 2; ++kc)
            cf[j][kc] = *(const bf16x8*)(WC + (size_t)(j * 64 + 16 * w + l15) * 64 + kc * 32 + l4 * 8);

    // stage Hl[col=(n*24+t)][kf]: kf 0..95 from H_k, 96..127 from x (bf16)
    for (int c = tid; c < 1152; c += 256) {
        int n = c / 288, rem = c % 288, k = rem / 96, i8 = rem % 96;
        int f = i8 / 3, t0 = (i8 % 3) * 8;
        u16x8 hv = *(const u16x8*)(H + (size_t)k * HS_ + (bn0 + n) * 768 + f * 24 + t0);
#pragma unroll
        for (int s = 0; s < 8; ++s)
            Hl[(n * 24 + t0 + s) * HLP_ + k * 32 + f] = hv[s];
    }
    for (int c = tid; c < 768; c += 256) {
        int n = c / 192, i4 = c % 192, f = i4 / 6, t0 = (i4 % 6) * 4;
        float4 xv = *(const float4*)(x + (bn0 + n) * 768 + f * 24 + t0);
        int base = (n * 24 + t0) * HLP_ + 96 + f;
        Hl[base] = f2bf(xv.x);
        Hl[base + HLP_] = f2bf(xv.y);
        Hl[base + 2 * HLP_] = f2bf(xv.z);
        Hl[base + 3 * HLP_] = f2bf(xv.w);
    }
    // Gl zero borders (tau=0,25 per n)
    for (int i = tid; i < 512; i += 256) {
        int n = i >> 7, r = (i >> 6) & 1, g = i & 63;
        Gl[(n * 26 + r * 25) * GLP_ + g] = 0;
    }
    if (tid < 64) {
        biasS[tid] = time_b[tid] + skip_b[tid];
        lgS[tid] = ln_g[tid];
        lbS[tid] = ln_b[tid];
    }
    __syncthreads();

    // stage 1: gcn (K=96) + skip (K=32), write relu(gcn) -> Gl bf16
    f32x4 accs[6];
#pragma unroll
    for (int ct = 0; ct < 6; ++ct) {
        int col = ct * 16 + l15;
        const unsigned short* hr = Hl + col * HLP_ + l4 * 8;
        bf16x8 h0 = *(const bf16x8*)(hr);
        bf16x8 h1 = *(const bf16x8*)(hr + 32);
        bf16x8 h2 = *(const bf16x8*)(hr + 64);
        bf16x8 h3 = *(const bf16x8*)(hr + 96);
        f32x4 g = (f32x4){0.f, 0.f, 0.f, 0.f};
        g = __builtin_amdgcn_mfma_f32_16x16x32_bf16(af[0], h0, g, 0, 0, 0);
        g = __builtin_amdgcn_mfma_f32_16x16x32_bf16(af[1], h1, g, 0, 0, 0);
        g = __builtin_amdgcn_mfma_f32_16x16x32_bf16(af[2], h2, g, 0, 0, 0);
        f32x4 s = (f32x4){0.f, 0.f, 0.f, 0.f};
        s = __builtin_amdgcn_mfma_f32_16x16x32_bf16(af[3], h3, s, 0, 0, 0);
        accs[ct] = s;
        int n = col / 24, t = col - n * 24;
        u16x4 pk;
#pragma unroll
        for (int r = 0; r < 4; ++r) pk[r] = f2bf(g[r] > 0.f ? g[r] : 0.f);
        *(u16x4*)(Gl + (n * 26 + t + 1) * GLP_ + 16 * w + 4 * l4) = pk;
    }
    __syncthreads();

    // stage 2: conv as 3 shifted GEMMs (K=64) + skip + bias + relu -> Tl fp32
    // (Tl aliases Hl, which is dead after stage 1)
#pragma unroll
    for (int ct = 0; ct < 6; ++ct) {
        int col = ct * 16 + l15;
        int n = col / 24, t = col - n * 24;
        f32x4 acc = accs[ct];
#pragma unroll
        for (int j = 0; j < 3; ++j) {
            const unsigned short* gr = Gl + (n * 26 + t + j) * GLP_ + l4 * 8;
            acc = __builtin_amdgcn_mfma_f32_16x16x32_bf16(cf[j][0], *(const bf16x8*)(gr), acc, 0, 0, 0);
            acc = __builtin_amdgcn_mfma_f32_16x16x32_bf16(cf[j][1], *(const bf16x8*)(gr + 32), acc, 0, 0, 0);
        }
        int cb = 16 * w + 4 * l4;
        f32x4 bv = *(const f32x4*)(biasS + cb);
        f32x4 o;
#pragma unroll
        for (int r = 0; r < 4; ++r) {
            float v = acc[r] + bv[r];
            o[r] = v > 0.f ? v : 0.f;
        }
        *(f32x4*)(Tl + col * TLP_ + cb) = o;
    }
    __syncthreads();

    // LN stats per column (n,t)
    if (tid < 96) {
        const float* tr = Tl + tid * TLP_;
        float sum = 0.f, sq = 0.f;
#pragma unroll
        for (int i = 0; i < 16; ++i) {
            f32x4 v = *(const f32x4*)(tr + 4 * i);
#pragma unroll
            for (int r = 0; r < 4; ++r) {
                sum += v[r];
                sq += v[r] * v[r];
            }
        }
        float mu = sum * (1.0f / 64.0f);
        float var = sq * (1.0f / 64.0f) - mu * mu;
        muS[tid] = mu;
        rsS[tid] = rsqrtf(var + 1e-5f);
    }
    __syncthreads();

    // coalesced store: out[((b*N+n)*64+c)*24+t], idx enumerates (n,c,t)
    float* ob = out + bn0 * (TC_ * Tt_);
    for (int idx = tid; idx < 6144; idx += 256) {
        int t = idx % 24;
        int c = (idx / 24) & 63;
        int n = idx / 1536;
        int col = n * 24 + t;
        float v = Tl[col * TLP_ + c];
        ob[idx] = (v - muS[col]) * rsS[col] * lgS[c] + lbS[c];
    }
}

extern "C" void kernel_launch(void* const* d_in, const int* in_sizes, int n_in,
                              void* d_out, int out_size, void* d_ws, size_t ws_size,
                              hipStream_t stream) {
    const float* x       = (const float*)d_in[0];
    const float* cheb    = (const float*)d_in[1];
    const float* w_cheb  = (const float*)d_in[2];
    const float* sa_wa   = (const float*)d_in[3];
    const float* sa_wb   = (const float*)d_in[4];
    const float* sa_wc   = (const float*)d_in[5];
    const float* sa_bias = (const float*)d_in[6];
    const float* sa_proj = (const float*)d_in[7];
    const float* ta_w1   = (const float*)d_in[8];
    const float* ta_w2   = (const float*)d_in[9];
    const float* ta_w3   = (const float*)d_in[10];
    const float* ta_bias = (const float*)d_in[11];
    const float* ta_proj = (const float*)d_in[12];
    const float* time_w  = (const float*)d_in[13];
    const float* time_b  = (const float*)d_in[14];
    const float* skip_w  = (const float*)d_in[15];
    const float* skip_b  = (const float*)d_in[16];
    const float* ln_g    = (const float*)d_in[17];
    const float* ln_b    = (const float*)d_in[18];
    float* out = (float*)d_out;

    float* ws    = (float*)d_ws;
    float* tmp   = ws;                      // 24576 f
    float* lhs_t = tmp + 24576;             // 393216 f
    float* rhs_t = lhs_t + 393216;          // 393216 f
    float* tw    = rhs_t + 393216;          // 18432 f
    float* lhs_s = tw + 18432;              // 393216 f
    float* rhs_s = lhs_s + 393216;          // 393216 f
    unsigned short* WAbuf = (unsigned short*)(rhs_s + 393216);   // 8192 us
    unsigned short* WCbuf = WAbuf + 8192;                        // 12288 us (fits 12288-f slot)
    float* attn  = rhs_s + 393216 + 12288;  // 8388608 f
    float* Sbuf  = attn + 8388608;          // 8388608 f
    unsigned short* XT = (unsigned short*)(Sbuf + 8388608);   // 12582912 us
    unsigned short* AT = XT + 12582912;                       // 8388608 us
    unsigned short* hbuf = (unsigned short*)((char*)attn + 109051904);  // 3 x 12582912 us

    kprep<<<1, 256, 0, stream>>>(w_cheb, skip_w, time_w, WAbuf, WCbuf);
    kxT<<<dim3(12, 8, 32), 256, 0, stream>>>(x, XT);
    ka_tmp<<<96, 256, 0, stream>>>(x, ta_w1, tmp);
    kb_rhs<<<1536, 256, 0, stream>>>(x, ta_w3, rhs_t);
    kc_lhs<<<1536, 256, 0, stream>>>(tmp, ta_w2, lhs_t);
    kd_temporal<<<32, 576, 0, stream>>>(lhs_t, rhs_t, ta_bias, ta_proj, tw);
    ke_spatial<<<dim3(512, 32), 256, 0, stream>>>(x, tw, sa_wa, sa_wb, sa_wc, lhs_s, rhs_s);
    kg_attn<<<dim3(32, 32), 256, 0, stream>>>(lhs_s, rhs_s, sa_bias, attn);
    kh_sgemm<<<dim3(8, 8, 32), 256, 0, stream>>>(sa_proj, attn, Sbuf);
    kj2<<<dim3(8, 32), 256, 0, stream>>>(Sbuf);
    for (int k = 0; k < 3; ++k) {
        kaT<<<dim3(8, 8, 32), 256, 0, stream>>>(cheb, Sbuf, AT, k);
        hgemm_mfma<<<dim3(6, 4, 32), 256, 0, stream>>>(AT, XT, hbuf + (size_t)k * 12582912);
    }
    ktail<<<dim3(128, 32), 256, 0, stream>>>(hbuf, x, WAbuf, WCbuf,
                                             time_b, skip_b, ln_g, ln_b, out);
}

// Round 4
// 569.044 us; speedup vs baseline: 3.0847x; 1.1809x over previous
//
#include <hip/hip_runtime.h>
#include <math.h>

#define Bb_ 32
#define Nn_ 512
#define Ff_ 32
#define Tt_ 24
#define GC_ 64
#define TC_ 64

typedef __attribute__((ext_vector_type(8))) short bf16x8;
typedef __attribute__((ext_vector_type(4))) float f32x4;
typedef __attribute__((ext_vector_type(8))) unsigned short u16x8;
typedef __attribute__((ext_vector_type(4))) unsigned short u16x4;

__device__ __forceinline__ float sigmoidf_(float v) { return 1.0f / (1.0f + __expf(-v)); }

__device__ __forceinline__ unsigned short f2bf(float f) {
    unsigned u = __float_as_uint(f);
    u = (u + 0x7fffu + ((u >> 16) & 1u)) >> 16;
    return (unsigned short)u;
}
__device__ __forceinline__ float bf2f(unsigned short h) {
    return __uint_as_float(((unsigned)h) << 16);
}

__device__ __forceinline__ void async16(const void* g, void* l) {
    __builtin_amdgcn_global_load_lds((const __attribute__((address_space(1))) unsigned int*)g,
                                     (__attribute__((address_space(3))) unsigned int*)l,
                                     16, 0, 0);
}

// ---------------- temporal attention pieces ----------------
__global__ void ka_tmp(const float* __restrict__ x, const float* __restrict__ w1,
                       float* __restrict__ tmp) {
    int tid = blockIdx.x * blockDim.x + threadIdx.x;
    int t = tid % Tt_;
    int f = (tid / Tt_) % Ff_;
    int b = tid / (Tt_ * Ff_);
    const float* xp = x + ((size_t)b * Nn_ * Ff_ + f) * Tt_ + t;
    float s = 0.f;
    for (int n = 0; n < Nn_; ++n) s += xp[(size_t)n * Ff_ * Tt_] * w1[n];
    tmp[(b * Tt_ + t) * Ff_ + f] = s;
}

__global__ void kb_rhs(const float* __restrict__ x, const float* __restrict__ w3,
                       float* __restrict__ rhs_t) {
    int tid = blockIdx.x * blockDim.x + threadIdx.x;
    int t = tid % Tt_;
    int n = (tid / Tt_) % Nn_;
    int b = tid / (Tt_ * Nn_);
    const float* xp = x + (((size_t)b * Nn_ + n) * Ff_) * Tt_ + t;
    float s = 0.f;
#pragma unroll
    for (int f = 0; f < Ff_; ++f) s += w3[f] * xp[f * Tt_];
    rhs_t[(b * Nn_ + n) * Tt_ + t] = s;
}

__global__ void kc_lhs(const float* __restrict__ tmp, const float* __restrict__ w2,
                       float* __restrict__ lhs_t) {
    int tid = blockIdx.x * blockDim.x + threadIdx.x;
    int n = tid % Nn_;
    int t = (tid / Nn_) % Tt_;
    int b = tid / (Nn_ * Tt_);
    const float* tp = tmp + (b * Tt_ + t) * Ff_;
    float s = 0.f;
#pragma unroll
    for (int f = 0; f < Ff_; ++f) s += tp[f] * w2[f * Nn_ + n];
    lhs_t[(b * Tt_ + t) * Nn_ + n] = s;
}

__global__ __launch_bounds__(576) void kd_temporal(const float* __restrict__ lhs_t,
                                                   const float* __restrict__ rhs_t,
                                                   const float* __restrict__ ta_bias,
                                                   const float* __restrict__ ta_proj,
                                                   float* __restrict__ temp_w) {
    __shared__ float rl[Nn_ * Tt_];
    __shared__ float sg[Tt_ * Tt_];
    __shared__ float Eb[Tt_ * Tt_];
    int b = blockIdx.x;
    int tid = threadIdx.x;
    for (int i = tid; i < Nn_ * Tt_; i += 576) rl[i] = rhs_t[b * Nn_ * Tt_ + i];
    __syncthreads();
    int u = tid % Tt_;
    int t = tid / Tt_;
    const float* lp = lhs_t + (b * Tt_ + t) * Nn_;
    float s = 0.f;
    for (int n = 0; n < Nn_; ++n) s += lp[n] * rl[n * Tt_ + u];
    sg[t * Tt_ + u] = sigmoidf_(s + ta_bias[t * Tt_ + u]);
    __syncthreads();
    float e = 0.f;
#pragma unroll
    for (int k = 0; k < Tt_; ++k) e += ta_proj[t * Tt_ + k] * sg[k * Tt_ + u];
    Eb[t * Tt_ + u] = e;
    __syncthreads();
    if (tid < Tt_) {
        int uu = tid;
        float m = -1e30f;
        for (int s2 = 0; s2 < Tt_; ++s2) m = fmaxf(m, Eb[s2 * Tt_ + uu]);
        float sum = 0.f;
        for (int s2 = 0; s2 < Tt_; ++s2) sum += __expf(Eb[s2 * Tt_ + uu] - m);
        float inv = 1.0f / sum;
        for (int s2 = 0; s2 < Tt_; ++s2)
            temp_w[b * Tt_ * Tt_ + s2 * Tt_ + uu] = __expf(Eb[s2 * Tt_ + uu] - m) * inv;
    }
}

__global__ __launch_bounds__(256) void ke_spatial(const float* __restrict__ x,
                                                  const float* __restrict__ tw,
                                                  const float* __restrict__ sa_wa,
                                                  const float* __restrict__ sa_wb,
                                                  const float* __restrict__ sa_wc,
                                                  float* __restrict__ lhs_s,
                                                  float* __restrict__ rhs_s) {
    __shared__ float xl[Ff_ * Tt_];
    __shared__ float twl[Tt_ * Tt_];
    __shared__ float xtl[Ff_ * Tt_];
    __shared__ float tmp2[Ff_];
    int n = blockIdx.x, b = blockIdx.y, tid = threadIdx.x;
    const float* xp = x + ((size_t)(b * Nn_ + n)) * Ff_ * Tt_;
    for (int i = tid; i < Ff_ * Tt_; i += 256) xl[i] = xp[i];
    for (int i = tid; i < Tt_ * Tt_; i += 256) twl[i] = tw[b * Tt_ * Tt_ + i];
    __syncthreads();
    for (int i = tid; i < Ff_ * Tt_; i += 256) {
        int f = i / Tt_, u = i % Tt_;
        float s = 0.f;
#pragma unroll
        for (int t = 0; t < Tt_; ++t) s += xl[f * Tt_ + t] * twl[t * Tt_ + u];
        xtl[i] = s;
    }
    __syncthreads();
    if (tid < Ff_) {
        float s = 0.f;
#pragma unroll
        for (int t = 0; t < Tt_; ++t) s += xtl[tid * Tt_ + t] * sa_wa[t];
        tmp2[tid] = s;
    }
    __syncthreads();
    if (tid < Tt_) {
        float a = 0.f, r = 0.f;
#pragma unroll
        for (int f = 0; f < Ff_; ++f) {
            a += tmp2[f] * sa_wb[f * Tt_ + tid];
            r += sa_wc[f] * xtl[f * Tt_ + tid];
        }
        int o = (b * Nn_ + n) * Tt_ + tid;
        lhs_s[o] = a;
        rhs_s[o] = r;
    }
}

// attnT[b][p][m] = sigmoid(lhs_s[m].rhs_s[p] + sa_bias[m][p]) split into bf16 hi/lo.
// block: 16 p-rows x 256 m-half. LDS-transposed bias tile, stride 17 (conflict-free).
__global__ __launch_bounds__(256) void kg_attnT(const float* __restrict__ lhs_s,
                                                const float* __restrict__ rhs_s,
                                                const float* __restrict__ sa_bias,
                                                unsigned short* __restrict__ aTh,
                                                unsigned short* __restrict__ aTl) {
    __shared__ float L[256 * 25];
    __shared__ float R[16 * Tt_];
    __shared__ float Bt[256 * 17];
    int b = blockIdx.y, tid = threadIdx.x;
    int p0 = (blockIdx.x >> 1) * 16;
    int m0 = (blockIdx.x & 1) * 256;
    for (int i = tid; i < 256 * Tt_; i += 256) {
        int m = i / Tt_, t = i - m * Tt_;
        L[m * 25 + t] = lhs_s[b * Nn_ * Tt_ + (m0 + m) * Tt_ + t];
    }
    for (int i = tid; i < 16 * Tt_; i += 256) R[i] = rhs_s[b * Nn_ * Tt_ + p0 * Tt_ + i];
    for (int i = tid; i < 256 * 16; i += 256) {
        int m = i >> 4, j = i & 15;
        Bt[m * 17 + j] = sa_bias[(size_t)(m0 + m) * Nn_ + p0 + j];
    }
    __syncthreads();
    for (int idx = tid; idx < 16 * 256; idx += 256) {
        int r = idx >> 8, mm = idx & 255;
        const float* lp = L + mm * 25;
        const float* rp = R + r * Tt_;
        float s = 0.f;
#pragma unroll
        for (int t = 0; t < Tt_; ++t) s += lp[t] * rp[t];
        float v = sigmoidf_(s + Bt[mm * 17 + r]);
        unsigned short hi = f2bf(v);
        size_t o = ((size_t)b * Nn_ + p0 + r) * Nn_ + m0 + mm;
        aTh[o] = hi;
        aTl[o] = f2bf(v - bf2f(hi));
    }
}

// proj hi/lo split (row-major [n][m], m-contiguous — already MFMA-B-ready)
__global__ void kprojsplit(const float* __restrict__ proj,
                           unsigned short* __restrict__ pBh,
                           unsigned short* __restrict__ pBl) {
    int i = blockIdx.x * 256 + threadIdx.x;   // 262144
    float v = proj[i];
    unsigned short hi = f2bf(v);
    pBh[i] = hi;
    pBl[i] = f2bf(v - bf2f(hi));
}

// chebT[k][p][m] = cheb[k][m][p]
__global__ __launch_bounds__(256) void kchebT(const float* __restrict__ cheb,
                                              float* __restrict__ chebT) {
    __shared__ float tl[64][65];
    int p0 = blockIdx.x * 64, m0 = blockIdx.y * 64, k = blockIdx.z;
    int tid = threadIdx.x, j = tid & 63, i4 = tid >> 6;
#pragma unroll
    for (int r = 0; r < 16; ++r) {
        int i = i4 + r * 4;
        tl[i][j] = cheb[(size_t)k * Nn_ * Nn_ + (size_t)(m0 + i) * Nn_ + p0 + j];
    }
    __syncthreads();
#pragma unroll
    for (int r = 0; r < 16; ++r) {
        int pp = i4 + r * 4;
        chebT[(size_t)k * Nn_ * Nn_ + (size_t)(p0 + pp) * Nn_ + m0 + j] = tl[j][pp];
    }
}

// ST[b][p][n] = sum_m attnT[b][p][m] * proj[n][m]  via split-bf16 MFMA
// (hi*hi + hi*lo + lo*hi; ~fp32 accuracy). 128x128 tiles.
__global__ __launch_bounds__(256) void ksgemm_mfma(const unsigned short* __restrict__ aTh,
                                                   const unsigned short* __restrict__ aTl,
                                                   const unsigned short* __restrict__ pBh,
                                                   const unsigned short* __restrict__ pBl,
                                                   float* __restrict__ ST) {
    __shared__ unsigned short Ah[512 * 8], Al[512 * 8], Bh[512 * 8], Bl[512 * 8];
    int b = blockIdx.z;
    int p0 = blockIdx.y * 128, n0 = blockIdx.x * 128;
    int tid = threadIdx.x, wid = tid >> 6, lane = tid & 63;
    int l15 = lane & 15, l4 = lane >> 4;
    int wm = (wid & 1) * 64, wn = (wid >> 1) * 64;
    const unsigned short* Abh = aTh + (size_t)b * Nn_ * Nn_;
    const unsigned short* Abl = aTl + (size_t)b * Nn_ * Nn_;

    int cp0 = wid * 128 + lane, cp1 = cp0 + 64;
    int r0 = cp0 >> 2, k0c = (cp0 & 3) ^ ((r0 >> 1) & 3);
    int r1 = cp1 >> 2, k1c = (cp1 & 3) ^ ((r1 >> 1) & 3);
    const unsigned short* gAh0 = Abh + (size_t)(p0 + r0) * Nn_ + k0c * 8;
    const unsigned short* gAh1 = Abh + (size_t)(p0 + r1) * Nn_ + k1c * 8;
    const unsigned short* gAl0 = Abl + (size_t)(p0 + r0) * Nn_ + k0c * 8;
    const unsigned short* gAl1 = Abl + (size_t)(p0 + r1) * Nn_ + k1c * 8;
    const unsigned short* gBh0 = pBh + (size_t)(n0 + r0) * Nn_ + k0c * 8;
    const unsigned short* gBh1 = pBh + (size_t)(n0 + r1) * Nn_ + k1c * 8;
    const unsigned short* gBl0 = pBl + (size_t)(n0 + r0) * Nn_ + k0c * 8;
    const unsigned short* gBl1 = pBl + (size_t)(n0 + r1) * Nn_ + k1c * 8;
    unsigned short* lAh0 = Ah + (size_t)cp0 * 8;
    unsigned short* lAh1 = Ah + (size_t)cp1 * 8;
    unsigned short* lAl0 = Al + (size_t)cp0 * 8;
    unsigned short* lAl1 = Al + (size_t)cp1 * 8;
    unsigned short* lBh0 = Bh + (size_t)cp0 * 8;
    unsigned short* lBh1 = Bh + (size_t)cp1 * 8;
    unsigned short* lBl0 = Bl + (size_t)cp0 * 8;
    unsigned short* lBl1 = Bl + (size_t)cp1 * 8;

    int ca[4], cb[4];
#pragma unroll
    for (int i = 0; i < 4; ++i) {
        int row = wm + i * 16 + l15;
        ca[i] = row * 4 + (l4 ^ ((row >> 1) & 3));
        row = wn + i * 16 + l15;
        cb[i] = row * 4 + (l4 ^ ((row >> 1) & 3));
    }

    f32x4 acc[4][4];
#pragma unroll
    for (int i = 0; i < 4; ++i)
#pragma unroll
        for (int j = 0; j < 4; ++j) acc[i][j] = (f32x4){0.f, 0.f, 0.f, 0.f};

    for (int ks = 0; ks < 16; ++ks) {
        __syncthreads();
        async16(gAh0 + ks * 32, lAh0);
        async16(gAh1 + ks * 32, lAh1);
        async16(gAl0 + ks * 32, lAl0);
        async16(gAl1 + ks * 32, lAl1);
        async16(gBh0 + ks * 32, lBh0);
        async16(gBh1 + ks * 32, lBh1);
        async16(gBl0 + ks * 32, lBl0);
        async16(gBl1 + ks * 32, lBl1);
        __syncthreads();
        bf16x8 ah[4], al[4], bh[4], bl[4];
#pragma unroll
        for (int i = 0; i < 4; ++i) {
            ah[i] = *(const bf16x8*)(Ah + (size_t)ca[i] * 8);
            al[i] = *(const bf16x8*)(Al + (size_t)ca[i] * 8);
        }
#pragma unroll
        for (int j = 0; j < 4; ++j) {
            bh[j] = *(const bf16x8*)(Bh + (size_t)cb[j] * 8);
            bl[j] = *(const bf16x8*)(Bl + (size_t)cb[j] * 8);
        }
#pragma unroll
        for (int i = 0; i < 4; ++i)
#pragma unroll
            for (int j = 0; j < 4; ++j) {
                acc[i][j] = __builtin_amdgcn_mfma_f32_16x16x32_bf16(ah[i], bh[j], acc[i][j], 0, 0, 0);
                acc[i][j] = __builtin_amdgcn_mfma_f32_16x16x32_bf16(ah[i], bl[j], acc[i][j], 0, 0, 0);
                acc[i][j] = __builtin_amdgcn_mfma_f32_16x16x32_bf16(al[i], bh[j], acc[i][j], 0, 0, 0);
            }
    }

    float* Cb = ST + (size_t)b * Nn_ * Nn_;
#pragma unroll
    for (int i = 0; i < 4; ++i)
#pragma unroll
        for (int j = 0; j < 4; ++j) {
            int p = p0 + wm + i * 16 + l4 * 4;
            int n = n0 + wn + j * 16 + l15;
#pragma unroll
            for (int r = 0; r < 4; ++r)
                Cb[(size_t)(p + r) * Nn_ + n] = acc[i][j][r];
        }
}

// row softmax over n of ST[b][p][n] (contiguous rows), one wave per row
__global__ __launch_bounds__(256) void kj3(float* __restrict__ ST) {
    int row = blockIdx.x * 4 + (threadIdx.x >> 6);
    int lane = threadIdx.x & 63;
    float* rp = ST + (size_t)row * Nn_ + lane * 8;
    float4 a = *(const float4*)rp;
    float4 c = *(const float4*)(rp + 4);
    float m = fmaxf(fmaxf(fmaxf(a.x, a.y), fmaxf(a.z, a.w)),
                    fmaxf(fmaxf(c.x, c.y), fmaxf(c.z, c.w)));
#pragma unroll
    for (int off = 32; off > 0; off >>= 1) m = fmaxf(m, __shfl_xor(m, off, 64));
    float e0 = __expf(a.x - m), e1 = __expf(a.y - m), e2 = __expf(a.z - m), e3 = __expf(a.w - m);
    float e4 = __expf(c.x - m), e5 = __expf(c.y - m), e6 = __expf(c.z - m), e7 = __expf(c.w - m);
    float s = e0 + e1 + e2 + e3 + e4 + e5 + e6 + e7;
#pragma unroll
    for (int off = 32; off > 0; off >>= 1) s += __shfl_xor(s, off, 64);
    float inv = 1.0f / s;
    *(float4*)rp = make_float4(e0 * inv, e1 * inv, e2 * inv, e3 * inv);
    *(float4*)(rp + 4) = make_float4(e4 * inv, e5 * inv, e6 * inv, e7 * inv);
}

// AT_k[b][p][m] bf16 = chebT[k][p][m] * spatT[b][p][m] — pure streaming
__global__ void kaT3(const float* __restrict__ ST, const float* __restrict__ chebT,
                     unsigned short* __restrict__ AT) {
    size_t i4 = ((size_t)blockIdx.x * 256 + threadIdx.x) * 4;   // over 32*512*512
    int b = (int)(i4 >> 18);
    int pm = (int)(i4 & 262143);
    float4 s = *(const float4*)(ST + (size_t)b * 262144 + pm);
#pragma unroll
    for (int k = 0; k < 3; ++k) {
        float4 cv = *(const float4*)(chebT + (size_t)k * 262144 + pm);
        u16x4 o;
        o[0] = f2bf(cv.x * s.x);
        o[1] = f2bf(cv.y * s.y);
        o[2] = f2bf(cv.z * s.z);
        o[3] = f2bf(cv.w * s.w);
        *(u16x4*)(AT + (size_t)k * 8388608 + (size_t)b * 262144 + pm) = o;
    }
}

// XT[b][q][m] bf16 = x[b][m][q]
__global__ __launch_bounds__(256) void kxT(const float* __restrict__ x,
                                           unsigned short* __restrict__ XT) {
    __shared__ float tl[64][65];
    int q0 = blockIdx.x * 64, m0 = blockIdx.y * 64, b = blockIdx.z;
    int tid = threadIdx.x, j = tid & 63, i4 = tid >> 6;
#pragma unroll
    for (int r = 0; r < 16; ++r) {
        int i = i4 + r * 4;
        tl[i][j] = x[((size_t)(b * Nn_ + m0 + i)) * 768 + q0 + j];
    }
    __syncthreads();
#pragma unroll
    for (int r = 0; r < 16; ++r) {
        int qq = i4 + r * 4;
        XT[((size_t)b * 768 + q0 + qq) * Nn_ + m0 + j] = f2bf(tl[j][qq]);
    }
}

// H[b][p][q] bf16 = sum_m AT[b][p][m] * XT[b][q][m]  — bf16 MFMA, 128x128 tile
__global__ __launch_bounds__(256) void hgemm_mfma(const unsigned short* __restrict__ AT,
                                                  const unsigned short* __restrict__ XT,
                                                  unsigned short* __restrict__ H) {
    __shared__ unsigned short As[512 * 8];
    __shared__ unsigned short Bs[512 * 8];
    int b = blockIdx.z;
    int p0 = blockIdx.y * 128;
    int q0 = blockIdx.x * 128;
    int tid = threadIdx.x;
    int wid = tid >> 6, lane = tid & 63;
    int l15 = lane & 15, l4 = lane >> 4;
    int wm = (wid & 1) * 64, wn = (wid >> 1) * 64;
    const unsigned short* Ab = AT + (size_t)b * Nn_ * Nn_;
    const unsigned short* Bb = XT + (size_t)b * 768 * Nn_;

    int cp0 = wid * 128 + lane;
    int cp1 = cp0 + 64;
    int rA0 = cp0 >> 2, kA0 = (cp0 & 3) ^ ((rA0 >> 1) & 3);
    int rA1 = cp1 >> 2, kA1 = (cp1 & 3) ^ ((rA1 >> 1) & 3);
    const unsigned short* gA0 = Ab + (size_t)(p0 + rA0) * Nn_ + kA0 * 8;
    const unsigned short* gA1 = Ab + (size_t)(p0 + rA1) * Nn_ + kA1 * 8;
    const unsigned short* gB0 = Bb + (size_t)(q0 + rA0) * Nn_ + kA0 * 8;
    const unsigned short* gB1 = Bb + (size_t)(q0 + rA1) * Nn_ + kA1 * 8;
    unsigned short* lA0 = As + (size_t)(wid * 128) * 8;
    unsigned short* lA1 = As + (size_t)(wid * 128 + 64) * 8;
    unsigned short* lB0 = Bs + (size_t)(wid * 128) * 8;
    unsigned short* lB1 = Bs + (size_t)(wid * 128 + 64) * 8;

    int ca[4], cb[4];
#pragma unroll
    for (int i = 0; i < 4; ++i) {
        int row = wm + i * 16 + l15;
        ca[i] = row * 4 + (l4 ^ ((row >> 1) & 3));
        row = wn + i * 16 + l15;
        cb[i] = row * 4 + (l4 ^ ((row >> 1) & 3));
    }

    f32x4 acc[4][4];
#pragma unroll
    for (int i = 0; i < 4; ++i)
#pragma unroll
        for (int j = 0; j < 4; ++j) acc[i][j] = (f32x4){0.f, 0.f, 0.f, 0.f};

    for (int ks = 0; ks < 16; ++ks) {
        __syncthreads();
        async16(gA0 + ks * 32, lA0);
        async16(gA1 + ks * 32, lA1);
        async16(gB0 + ks * 32, lB0);
        async16(gB1 + ks * 32, lB1);
        __syncthreads();
        bf16x8 af[4], bfv[4];
#pragma unroll
        for (int i = 0; i < 4; ++i) af[i] = *(const bf16x8*)(As + (size_t)ca[i] * 8);
#pragma unroll
        for (int j = 0; j < 4; ++j) bfv[j] = *(const bf16x8*)(Bs + (size_t)cb[j] * 8);
#pragma unroll
        for (int i = 0; i < 4; ++i)
#pragma unroll
            for (int j = 0; j < 4; ++j)
                acc[i][j] = __builtin_amdgcn_mfma_f32_16x16x32_bf16(af[i], bfv[j], acc[i][j], 0, 0, 0);
    }

    unsigned short* Hb = H + (size_t)b * Nn_ * 768;
#pragma unroll
    for (int i = 0; i < 4; ++i)
#pragma unroll
        for (int j = 0; j < 4; ++j) {
            int p = p0 + wm + i * 16 + l4 * 4;
            int q = q0 + wn + j * 16 + l15;
#pragma unroll
            for (int r = 0; r < 4; ++r)
                Hb[(size_t)(p + r) * 768 + q] = f2bf(acc[i][j][r]);
        }
}

// prep: WA[r][kf] bf16 (kf<96: w_cheb[kf][r]; kf>=96: skip_w[r][kf-96])
//       WC[(j*64+c)][g] bf16 = time_w[c][g][j]
__global__ void kprep(const float* __restrict__ wch, const float* __restrict__ skw,
                      const float* __restrict__ tw,
                      unsigned short* __restrict__ WA, unsigned short* __restrict__ WC) {
    int tid = threadIdx.x;
    for (int i = tid; i < 64 * 128; i += 256) {
        int r = i >> 7, kf = i & 127;
        float v = (kf < 96) ? wch[kf * 64 + r] : skw[r * 32 + (kf - 96)];
        WA[i] = f2bf(v);
    }
    for (int i = tid; i < 192 * 64; i += 256) {
        int j = i / 4096, c = (i >> 6) & 63, g = i & 63;
        WC[i] = f2bf(tw[c * 192 + g * 3 + j]);
    }
}

// -------- fused tail: gcn=relu(H·W), 1x3 conv (3 shifted GEMMs), skip, bias,
// relu, layernorm(c), transposed coalesced store. One block = 1 b x 4 n. -----
#define HS_ 12582912
#define HLP_ 136
#define GLP_ 72
#define TLP_ 68
__global__ __launch_bounds__(256) void ktail(const unsigned short* __restrict__ H,
                                             const float* __restrict__ x,
                                             const unsigned short* __restrict__ WA,
                                             const unsigned short* __restrict__ WC,
                                             const float* __restrict__ time_b,
                                             const float* __restrict__ skip_b,
                                             const float* __restrict__ ln_g,
                                             const float* __restrict__ ln_b,
                                             float* __restrict__ out) {
    __shared__ __align__(16) char pool_[96 * HLP_ * 2];
    __shared__ __align__(16) unsigned short Gl[104 * GLP_];
    __shared__ float biasS[64], lgS[64], lbS[64];
    __shared__ float muS[96], rsS[96];
    unsigned short* Hl = (unsigned short*)pool_;
    float* Tl = (float*)pool_;

    int b = blockIdx.y;
    int n0 = blockIdx.x * 4;
    size_t bn0 = (size_t)b * Nn_ + n0;
    int tid = threadIdx.x;
    int w = tid >> 6, lane = tid & 63, l15 = lane & 15, l4 = lane >> 4;

    bf16x8 af[4], cf[3][2];
#pragma unroll
    for (int q = 0; q < 4; ++q)
        af[q] = *(const bf16x8*)(WA + (size_t)(16 * w + l15) * 128 + q * 32 + l4 * 8);
#pragma unroll
    for (int j = 0; j < 3; ++j)
#pragma unroll
        for (int kc = 0; kc < 2; ++kc)
            cf[j][kc] = *(const bf16x8*)(WC + (size_t)(j * 64 + 16 * w + l15) * 64 + kc * 32 + l4 * 8);

    for (int c = tid; c < 1152; c += 256) {
        int n = c / 288, rem = c % 288, k = rem / 96, i8 = rem % 96;
        int f = i8 / 3, t0 = (i8 % 3) * 8;
        u16x8 hv = *(const u16x8*)(H + (size_t)k * HS_ + (bn0 + n) * 768 + f * 24 + t0);
#pragma unroll
        for (int s = 0; s < 8; ++s)
            Hl[(n * 24 + t0 + s) * HLP_ + k * 32 + f] = hv[s];
    }
    for (int c = tid; c < 768; c += 256) {
        int n = c / 192, i4 = c % 192, f = i4 / 6, t0 = (i4 % 6) * 4;
        float4 xv = *(const float4*)(x + (bn0 + n) * 768 + f * 24 + t0);
        int base = (n * 24 + t0) * HLP_ + 96 + f;
        Hl[base] = f2bf(xv.x);
        Hl[base + HLP_] = f2bf(xv.y);
        Hl[base + 2 * HLP_] = f2bf(xv.z);
        Hl[base + 3 * HLP_] = f2bf(xv.w);
    }
    for (int i = tid; i < 512; i += 256) {
        int n = i >> 7, r = (i >> 6) & 1, g = i & 63;
        Gl[(n * 26 + r * 25) * GLP_ + g] = 0;
    }
    if (tid < 64) {
        biasS[tid] = time_b[tid] + skip_b[tid];
        lgS[tid] = ln_g[tid];
        lbS[tid] = ln_b[tid];
    }
    __syncthreads();

    f32x4 accs[6];
#pragma unroll
    for (int ct = 0; ct < 6; ++ct) {
        int col = ct * 16 + l15;
        const unsigned short* hr = Hl + col * HLP_ + l4 * 8;
        bf16x8 h0 = *(const bf16x8*)(hr);
        bf16x8 h1 = *(const bf16x8*)(hr + 32);
        bf16x8 h2 = *(const bf16x8*)(hr + 64);
        bf16x8 h3 = *(const bf16x8*)(hr + 96);
        f32x4 g = (f32x4){0.f, 0.f, 0.f, 0.f};
        g = __builtin_amdgcn_mfma_f32_16x16x32_bf16(af[0], h0, g, 0, 0, 0);
        g = __builtin_amdgcn_mfma_f32_16x16x32_bf16(af[1], h1, g, 0, 0, 0);
        g = __builtin_amdgcn_mfma_f32_16x16x32_bf16(af[2], h2, g, 0, 0, 0);
        f32x4 s = (f32x4){0.f, 0.f, 0.f, 0.f};
        s = __builtin_amdgcn_mfma_f32_16x16x32_bf16(af[3], h3, s, 0, 0, 0);
        accs[ct] = s;
        int n = col / 24, t = col - n * 24;
        u16x4 pk;
#pragma unroll
        for (int r = 0; r < 4; ++r) pk[r] = f2bf(g[r] > 0.f ? g[r] : 0.f);
        *(u16x4*)(Gl + (n * 26 + t + 1) * GLP_ + 16 * w + 4 * l4) = pk;
    }
    __syncthreads();

#pragma unroll
    for (int ct = 0; ct < 6; ++ct) {
        int col = ct * 16 + l15;
        int n = col / 24, t = col - n * 24;
        f32x4 acc = accs[ct];
#pragma unroll
        for (int j = 0; j < 3; ++j) {
            const unsigned short* gr = Gl + (n * 26 + t + j) * GLP_ + l4 * 8;
            acc = __builtin_amdgcn_mfma_f32_16x16x32_bf16(cf[j][0], *(const bf16x8*)(gr), acc, 0, 0, 0);
            acc = __builtin_amdgcn_mfma_f32_16x16x32_bf16(cf[j][1], *(const bf16x8*)(gr + 32), acc, 0, 0, 0);
        }
        int cb = 16 * w + 4 * l4;
        f32x4 bv = *(const f32x4*)(biasS + cb);
        f32x4 o;
#pragma unroll
        for (int r = 0; r < 4; ++r) {
            float v = acc[r] + bv[r];
            o[r] = v > 0.f ? v : 0.f;
        }
        *(f32x4*)(Tl + col * TLP_ + cb) = o;
    }
    __syncthreads();

    if (tid < 96) {
        const float* tr = Tl + tid * TLP_;
        float sum = 0.f, sq = 0.f;
#pragma unroll
        for (int i = 0; i < 16; ++i) {
            f32x4 v = *(const f32x4*)(tr + 4 * i);
#pragma unroll
            for (int r = 0; r < 4; ++r) {
                sum += v[r];
                sq += v[r] * v[r];
            }
        }
        float mu = sum * (1.0f / 64.0f);
        float var = sq * (1.0f / 64.0f) - mu * mu;
        muS[tid] = mu;
        rsS[tid] = rsqrtf(var + 1e-5f);
    }
    __syncthreads();

    float* ob = out + bn0 * (TC_ * Tt_);
    for (int idx = tid; idx < 6144; idx += 256) {
        int t = idx % 24;
        int c = (idx / 24) & 63;
        int n = idx / 1536;
        int col = n * 24 + t;
        float v = Tl[col * TLP_ + c];
        ob[idx] = (v - muS[col]) * rsS[col] * lgS[c] + lbS[c];
    }
}

extern "C" void kernel_launch(void* const* d_in, const int* in_sizes, int n_in,
                              void* d_out, int out_size, void* d_ws, size_t ws_size,
                              hipStream_t stream) {
    const float* x       = (const float*)d_in[0];
    const float* cheb    = (const float*)d_in[1];
    const float* w_cheb  = (const float*)d_in[2];
    const float* sa_wa   = (const float*)d_in[3];
    const float* sa_wb   = (const float*)d_in[4];
    const float* sa_wc   = (const float*)d_in[5];
    const float* sa_bias = (const float*)d_in[6];
    const float* sa_proj = (const float*)d_in[7];
    const float* ta_w1   = (const float*)d_in[8];
    const float* ta_w2   = (const float*)d_in[9];
    const float* ta_w3   = (const float*)d_in[10];
    const float* ta_bias = (const float*)d_in[11];
    const float* ta_proj = (const float*)d_in[12];
    const float* time_w  = (const float*)d_in[13];
    const float* time_b  = (const float*)d_in[14];
    const float* skip_w  = (const float*)d_in[15];
    const float* skip_b  = (const float*)d_in[16];
    const float* ln_g    = (const float*)d_in[17];
    const float* ln_b    = (const float*)d_in[18];
    float* out = (float*)d_out;

    // ---- workspace layout (~195 MB) ----
    float* cur   = (float*)d_ws;
    float* tmp   = cur;            cur += 24576;
    float* lhs_t = cur;            cur += 393216;
    float* rhs_t = cur;            cur += 393216;
    float* tw    = cur;            cur += 18432;
    float* lhs_s = cur;            cur += 393216;
    float* rhs_s = cur;            cur += 393216;
    unsigned short* WAbuf = (unsigned short*)cur;            // 8192 us
    unsigned short* WCbuf = WAbuf + 8192;                    // 12288 us
    cur += 10240;
    unsigned short* pBh = (unsigned short*)cur;              // 262144 us
    unsigned short* pBl = pBh + 262144;                      // 262144 us
    cur += 262144;
    float* chebT = cur;            cur += 786432;
    unsigned short* regionA = (unsigned short*)cur;          // 25165824 us (attnT hi/lo, then AT x3)
    unsigned short* aTh = regionA;
    unsigned short* aTl = regionA + 8388608;
    unsigned short* ATb = regionA;
    cur += 12582912;
    float* STbuf = cur;            cur += 8388608;
    unsigned short* XT = (unsigned short*)cur;               // 12582912 us
    cur += 6291456;
    unsigned short* hbuf = (unsigned short*)cur;             // 37748736 us

    kprep<<<1, 256, 0, stream>>>(w_cheb, skip_w, time_w, WAbuf, WCbuf);
    kprojsplit<<<1024, 256, 0, stream>>>(sa_proj, pBh, pBl);
    kchebT<<<dim3(8, 8, 3), 256, 0, stream>>>(cheb, chebT);
    kxT<<<dim3(12, 8, 32), 256, 0, stream>>>(x, XT);
    ka_tmp<<<96, 256, 0, stream>>>(x, ta_w1, tmp);
    kb_rhs<<<1536, 256, 0, stream>>>(x, ta_w3, rhs_t);
    kc_lhs<<<1536, 256, 0, stream>>>(tmp, ta_w2, lhs_t);
    kd_temporal<<<32, 576, 0, stream>>>(lhs_t, rhs_t, ta_bias, ta_proj, tw);
    ke_spatial<<<dim3(512, 32), 256, 0, stream>>>(x, tw, sa_wa, sa_wb, sa_wc, lhs_s, rhs_s);
    kg_attnT<<<dim3(64, 32), 256, 0, stream>>>(lhs_s, rhs_s, sa_bias, aTh, aTl);
    ksgemm_mfma<<<dim3(4, 4, 32), 256, 0, stream>>>(aTh, aTl, pBh, pBl, STbuf);
    kj3<<<4096, 256, 0, stream>>>(STbuf);
    kaT3<<<8192, 256, 0, stream>>>(STbuf, chebT, ATb);
    for (int k = 0; k < 3; ++k) {
        hgemm_mfma<<<dim3(6, 4, 32), 256, 0, stream>>>(ATb + (size_t)k * 8388608, XT,
                                                       hbuf + (size_t)k * HS_);
    }
    ktail<<<dim3(128, 32), 256, 0, stream>>>(hbuf, x, WAbuf, WCbuf,
                                             time_b, skip_b, ln_g, ln_b, out);
}

// Round 5
// 506.637 us; speedup vs baseline: 3.4647x; 1.1232x over previous
//
#include <hip/hip_runtime.h>
#include <math.h>

#define Bb_ 32
#define Nn_ 512
#define Ff_ 32
#define Tt_ 24
#define GC_ 64
#define TC_ 64
#define HS_ 12582912

typedef __attribute__((ext_vector_type(8))) short bf16x8;
typedef __attribute__((ext_vector_type(4))) float f32x4;
typedef __attribute__((ext_vector_type(8))) unsigned short u16x8;
typedef __attribute__((ext_vector_type(4))) unsigned short u16x4;

__device__ __forceinline__ float sigmoidf_(float v) { return 1.0f / (1.0f + __expf(-v)); }

__device__ __forceinline__ unsigned short f2bf(float f) {
    unsigned u = __float_as_uint(f);
    u = (u + 0x7fffu + ((u >> 16) & 1u)) >> 16;
    return (unsigned short)u;
}
__device__ __forceinline__ float bf2f(unsigned short h) {
    return __uint_as_float(((unsigned)h) << 16);
}

__device__ __forceinline__ void async16(const void* g, void* l) {
    __builtin_amdgcn_global_load_lds((const __attribute__((address_space(1))) unsigned int*)g,
                                     (__attribute__((address_space(3))) unsigned int*)l,
                                     16, 0, 0);
}

// fused ka_tmp + kb_rhs: one pass over x.
// tmp[b,t,f] += w1[n]*x[b,n,f,t] (atomic, tmp pre-zeroed by kprep)
// rhs_t[b,n,t] = sum_f w3[f]*x[b,n,f,t]
__global__ __launch_bounds__(256) void kab(const float* __restrict__ x,
                                           const float* __restrict__ w1,
                                           const float* __restrict__ w3,
                                           float* __restrict__ tmp,
                                           float* __restrict__ rhs_t) {
    __shared__ float xr[768];
    __shared__ float w3S[32];
    int b = blockIdx.y, n0 = blockIdx.x * 32, tid = threadIdx.x;
    if (tid < 32) w3S[tid] = w3[tid];
    float a0 = 0.f, a1 = 0.f, a2 = 0.f;
    for (int it = 0; it < 32; ++it) {
        int n = n0 + it;
        const float* xp = x + ((size_t)(b * Nn_ + n)) * 768;
        float v0 = xp[tid], v1 = xp[tid + 256], v2 = xp[tid + 512];
        float w = w1[n];
        a0 += w * v0;
        a1 += w * v1;
        a2 += w * v2;
        __syncthreads();
        xr[tid] = v0;
        xr[tid + 256] = v1;
        xr[tid + 512] = v2;
        __syncthreads();
        if (tid < 24) {
            float s = 0.f;
#pragma unroll
            for (int f = 0; f < 32; ++f) s += w3S[f] * xr[f * 24 + tid];
            rhs_t[(b * Nn_ + n) * Tt_ + tid] = s;
        }
    }
    // acc index i corresponds to x offset i = f*24+t; tmp layout [b][t*32+f]
    {
        int i = tid;
        int f = i / 24, t = i - f * 24;
        atomicAdd(tmp + b * 768 + t * 32 + f, a0);
        i = tid + 256;
        f = i / 24; t = i - f * 24;
        atomicAdd(tmp + b * 768 + t * 32 + f, a1);
        i = tid + 512;
        f = i / 24; t = i - f * 24;
        atomicAdd(tmp + b * 768 + t * 32 + f, a2);
    }
}

__global__ void kc_lhs(const float* __restrict__ tmp, const float* __restrict__ w2,
                       float* __restrict__ lhs_t) {
    int tid = blockIdx.x * blockDim.x + threadIdx.x;
    int n = tid % Nn_;
    int t = (tid / Nn_) % Tt_;
    int b = tid / (Nn_ * Tt_);
    const float* tp = tmp + (b * Tt_ + t) * Ff_;
    float s = 0.f;
#pragma unroll
    for (int f = 0; f < Ff_; ++f) s += tp[f] * w2[f * Nn_ + n];
    lhs_t[(b * Tt_ + t) * Nn_ + n] = s;
}

__global__ __launch_bounds__(576) void kd_temporal(const float* __restrict__ lhs_t,
                                                   const float* __restrict__ rhs_t,
                                                   const float* __restrict__ ta_bias,
                                                   const float* __restrict__ ta_proj,
                                                   float* __restrict__ temp_w) {
    __shared__ float rl[Nn_ * Tt_];
    __shared__ float sg[Tt_ * Tt_];
    __shared__ float Eb[Tt_ * Tt_];
    int b = blockIdx.x;
    int tid = threadIdx.x;
    for (int i = tid; i < Nn_ * Tt_; i += 576) rl[i] = rhs_t[b * Nn_ * Tt_ + i];
    __syncthreads();
    int u = tid % Tt_;
    int t = tid / Tt_;
    const float* lp = lhs_t + (b * Tt_ + t) * Nn_;
    float s = 0.f;
    for (int n = 0; n < Nn_; ++n) s += lp[n] * rl[n * Tt_ + u];
    sg[t * Tt_ + u] = sigmoidf_(s + ta_bias[t * Tt_ + u]);
    __syncthreads();
    float e = 0.f;
#pragma unroll
    for (int k = 0; k < Tt_; ++k) e += ta_proj[t * Tt_ + k] * sg[k * Tt_ + u];
    Eb[t * Tt_ + u] = e;
    __syncthreads();
    if (tid < Tt_) {
        int uu = tid;
        float m = -1e30f;
        for (int s2 = 0; s2 < Tt_; ++s2) m = fmaxf(m, Eb[s2 * Tt_ + uu]);
        float sum = 0.f;
        for (int s2 = 0; s2 < Tt_; ++s2) sum += __expf(Eb[s2 * Tt_ + uu] - m);
        float inv = 1.0f / sum;
        for (int s2 = 0; s2 < Tt_; ++s2)
            temp_w[b * Tt_ * Tt_ + s2 * Tt_ + uu] = __expf(Eb[s2 * Tt_ + uu] - m) * inv;
    }
}

__global__ __launch_bounds__(256) void ke_spatial(const float* __restrict__ x,
                                                  const float* __restrict__ tw,
                                                  const float* __restrict__ sa_wa,
                                                  const float* __restrict__ sa_wb,
                                                  const float* __restrict__ sa_wc,
                                                  float* __restrict__ lhs_s,
                                                  float* __restrict__ rhs_s) {
    __shared__ float xl[Ff_ * Tt_];
    __shared__ float twl[Tt_ * Tt_];
    __shared__ float xtl[Ff_ * Tt_];
    __shared__ float tmp2[Ff_];
    int n = blockIdx.x, b = blockIdx.y, tid = threadIdx.x;
    const float* xp = x + ((size_t)(b * Nn_ + n)) * Ff_ * Tt_;
    for (int i = tid; i < Ff_ * Tt_; i += 256) xl[i] = xp[i];
    for (int i = tid; i < Tt_ * Tt_; i += 256) twl[i] = tw[b * Tt_ * Tt_ + i];
    __syncthreads();
    for (int i = tid; i < Ff_ * Tt_; i += 256) {
        int f = i / Tt_, u = i % Tt_;
        float s = 0.f;
#pragma unroll
        for (int t = 0; t < Tt_; ++t) s += xl[f * Tt_ + t] * twl[t * Tt_ + u];
        xtl[i] = s;
    }
    __syncthreads();
    if (tid < Ff_) {
        float s = 0.f;
#pragma unroll
        for (int t = 0; t < Tt_; ++t) s += xtl[tid * Tt_ + t] * sa_wa[t];
        tmp2[tid] = s;
    }
    __syncthreads();
    if (tid < Tt_) {
        float a = 0.f, r = 0.f;
#pragma unroll
        for (int f = 0; f < Ff_; ++f) {
            a += tmp2[f] * sa_wb[f * Tt_ + tid];
            r += sa_wc[f] * xtl[f * Tt_ + tid];
        }
        int o = (b * Nn_ + n) * Tt_ + tid;
        lhs_s[o] = a;
        rhs_s[o] = r;
    }
}

// attnT[b][p][m] = sigmoid(lhs_s[m].rhs_s[p] + sa_bias[m][p]) split into bf16 hi/lo
__global__ __launch_bounds__(256) void kg_attnT(const float* __restrict__ lhs_s,
                                                const float* __restrict__ rhs_s,
                                                const float* __restrict__ sa_bias,
                                                unsigned short* __restrict__ aTh,
                                                unsigned short* __restrict__ aTl) {
    __shared__ float L[256 * 25];
    __shared__ float R[16 * Tt_];
    __shared__ float Bt[256 * 17];
    int b = blockIdx.y, tid = threadIdx.x;
    int p0 = (blockIdx.x >> 1) * 16;
    int m0 = (blockIdx.x & 1) * 256;
    for (int i = tid; i < 256 * Tt_; i += 256) {
        int m = i / Tt_, t = i - m * Tt_;
        L[m * 25 + t] = lhs_s[b * Nn_ * Tt_ + (m0 + m) * Tt_ + t];
    }
    for (int i = tid; i < 16 * Tt_; i += 256) R[i] = rhs_s[b * Nn_ * Tt_ + p0 * Tt_ + i];
    for (int i = tid; i < 256 * 16; i += 256) {
        int m = i >> 4, j = i & 15;
        Bt[m * 17 + j] = sa_bias[(size_t)(m0 + m) * Nn_ + p0 + j];
    }
    __syncthreads();
    for (int idx = tid; idx < 16 * 256; idx += 256) {
        int r = idx >> 8, mm = idx & 255;
        const float* lp = L + mm * 25;
        const float* rp = R + r * Tt_;
        float s = 0.f;
#pragma unroll
        for (int t = 0; t < Tt_; ++t) s += lp[t] * rp[t];
        float v = sigmoidf_(s + Bt[mm * 17 + r]);
        unsigned short hi = f2bf(v);
        size_t o = ((size_t)b * Nn_ + p0 + r) * Nn_ + m0 + mm;
        aTh[o] = hi;
        aTl[o] = f2bf(v - bf2f(hi));
    }
}

__global__ void kprojsplit(const float* __restrict__ proj,
                           unsigned short* __restrict__ pBh,
                           unsigned short* __restrict__ pBl) {
    int i = blockIdx.x * 256 + threadIdx.x;
    float v = proj[i];
    unsigned short hi = f2bf(v);
    pBh[i] = hi;
    pBl[i] = f2bf(v - bf2f(hi));
}

// chebT[k][p][m] = cheb[k][m][p]
__global__ __launch_bounds__(256) void kchebT(const float* __restrict__ cheb,
                                              float* __restrict__ chebT) {
    __shared__ float tl[64][65];
    int p0 = blockIdx.x * 64, m0 = blockIdx.y * 64, k = blockIdx.z;
    int tid = threadIdx.x, j = tid & 63, i4 = tid >> 6;
#pragma unroll
    for (int r = 0; r < 16; ++r) {
        int i = i4 + r * 4;
        tl[i][j] = cheb[(size_t)k * Nn_ * Nn_ + (size_t)(m0 + i) * Nn_ + p0 + j];
    }
    __syncthreads();
#pragma unroll
    for (int r = 0; r < 16; ++r) {
        int pp = i4 + r * 4;
        chebT[(size_t)k * Nn_ * Nn_ + (size_t)(p0 + pp) * Nn_ + m0 + j] = tl[j][pp];
    }
}

// ST[b][p][n] = sum_m attnT[b][p][m] * proj[n][m]  via split-bf16 MFMA
__global__ __launch_bounds__(256) void ksgemm_mfma(const unsigned short* __restrict__ aTh,
                                                   const unsigned short* __restrict__ aTl,
                                                   const unsigned short* __restrict__ pBh,
                                                   const unsigned short* __restrict__ pBl,
                                                   float* __restrict__ ST) {
    __shared__ unsigned short Ah[512 * 8], Al[512 * 8], Bh[512 * 8], Bl[512 * 8];
    int b = blockIdx.z;
    int p0 = blockIdx.y * 128, n0 = blockIdx.x * 128;
    int tid = threadIdx.x, wid = tid >> 6, lane = tid & 63;
    int l15 = lane & 15, l4 = lane >> 4;
    int wm = (wid & 1) * 64, wn = (wid >> 1) * 64;
    const unsigned short* Abh = aTh + (size_t)b * Nn_ * Nn_;
    const unsigned short* Abl = aTl + (size_t)b * Nn_ * Nn_;

    int cp0 = wid * 128 + lane, cp1 = cp0 + 64;
    int r0 = cp0 >> 2, k0c = (cp0 & 3) ^ ((r0 >> 1) & 3);
    int r1 = cp1 >> 2, k1c = (cp1 & 3) ^ ((r1 >> 1) & 3);
    const unsigned short* gAh0 = Abh + (size_t)(p0 + r0) * Nn_ + k0c * 8;
    const unsigned short* gAh1 = Abh + (size_t)(p0 + r1) * Nn_ + k1c * 8;
    const unsigned short* gAl0 = Abl + (size_t)(p0 + r0) * Nn_ + k0c * 8;
    const unsigned short* gAl1 = Abl + (size_t)(p0 + r1) * Nn_ + k1c * 8;
    const unsigned short* gBh0 = pBh + (size_t)(n0 + r0) * Nn_ + k0c * 8;
    const unsigned short* gBh1 = pBh + (size_t)(n0 + r1) * Nn_ + k1c * 8;
    const unsigned short* gBl0 = pBl + (size_t)(n0 + r0) * Nn_ + k0c * 8;
    const unsigned short* gBl1 = pBl + (size_t)(n0 + r1) * Nn_ + k1c * 8;
    unsigned short* lAh0 = Ah + (size_t)cp0 * 8;
    unsigned short* lAh1 = Ah + (size_t)cp1 * 8;
    unsigned short* lAl0 = Al + (size_t)cp0 * 8;
    unsigned short* lAl1 = Al + (size_t)cp1 * 8;
    unsigned short* lBh0 = Bh + (size_t)cp0 * 8;
    unsigned short* lBh1 = Bh + (size_t)cp1 * 8;
    unsigned short* lBl0 = Bl + (size_t)cp0 * 8;
    unsigned short* lBl1 = Bl + (size_t)cp1 * 8;

    int ca[4], cb[4];
#pragma unroll
    for (int i = 0; i < 4; ++i) {
        int row = wm + i * 16 + l15;
        ca[i] = row * 4 + (l4 ^ ((row >> 1) & 3));
        row = wn + i * 16 + l15;
        cb[i] = row * 4 + (l4 ^ ((row >> 1) & 3));
    }

    f32x4 acc[4][4];
#pragma unroll
    for (int i = 0; i < 4; ++i)
#pragma unroll
        for (int j = 0; j < 4; ++j) acc[i][j] = (f32x4){0.f, 0.f, 0.f, 0.f};

    for (int ks = 0; ks < 16; ++ks) {
        __syncthreads();
        async16(gAh0 + ks * 32, lAh0);
        async16(gAh1 + ks * 32, lAh1);
        async16(gAl0 + ks * 32, lAl0);
        async16(gAl1 + ks * 32, lAl1);
        async16(gBh0 + ks * 32, lBh0);
        async16(gBh1 + ks * 32, lBh1);
        async16(gBl0 + ks * 32, lBl0);
        async16(gBl1 + ks * 32, lBl1);
        __syncthreads();
        bf16x8 ah[4], al[4], bh[4], bl[4];
#pragma unroll
        for (int i = 0; i < 4; ++i) {
            ah[i] = *(const bf16x8*)(Ah + (size_t)ca[i] * 8);
            al[i] = *(const bf16x8*)(Al + (size_t)ca[i] * 8);
        }
#pragma unroll
        for (int j = 0; j < 4; ++j) {
            bh[j] = *(const bf16x8*)(Bh + (size_t)cb[j] * 8);
            bl[j] = *(const bf16x8*)(Bl + (size_t)cb[j] * 8);
        }
#pragma unroll
        for (int i = 0; i < 4; ++i)
#pragma unroll
            for (int j = 0; j < 4; ++j) {
                acc[i][j] = __builtin_amdgcn_mfma_f32_16x16x32_bf16(ah[i], bh[j], acc[i][j], 0, 0, 0);
                acc[i][j] = __builtin_amdgcn_mfma_f32_16x16x32_bf16(ah[i], bl[j], acc[i][j], 0, 0, 0);
                acc[i][j] = __builtin_amdgcn_mfma_f32_16x16x32_bf16(al[i], bh[j], acc[i][j], 0, 0, 0);
            }
    }

    float* Cb = ST + (size_t)b * Nn_ * Nn_;
#pragma unroll
    for (int i = 0; i < 4; ++i)
#pragma unroll
        for (int j = 0; j < 4; ++j) {
            int p = p0 + wm + i * 16 + l4 * 4;
            int n = n0 + wn + j * 16 + l15;
#pragma unroll
            for (int r = 0; r < 4; ++r)
                Cb[(size_t)(p + r) * Nn_ + n] = acc[i][j][r];
        }
}

// fused row-softmax + cheb multiply + bf16 AT write (one wave per ST row)
__global__ __launch_bounds__(256) void kjaT(const float* __restrict__ ST,
                                            const float* __restrict__ chebT,
                                            unsigned short* __restrict__ AT) {
    int row = blockIdx.x * 4 + (threadIdx.x >> 6);   // b*512 + p
    int lane = threadIdx.x & 63;
    const float* rp = ST + (size_t)row * Nn_ + lane * 8;
    float4 a = *(const float4*)rp;
    float4 c = *(const float4*)(rp + 4);
    float m = fmaxf(fmaxf(fmaxf(a.x, a.y), fmaxf(a.z, a.w)),
                    fmaxf(fmaxf(c.x, c.y), fmaxf(c.z, c.w)));
#pragma unroll
    for (int off = 32; off > 0; off >>= 1) m = fmaxf(m, __shfl_xor(m, off, 64));
    float e[8];
    e[0] = __expf(a.x - m); e[1] = __expf(a.y - m); e[2] = __expf(a.z - m); e[3] = __expf(a.w - m);
    e[4] = __expf(c.x - m); e[5] = __expf(c.y - m); e[6] = __expf(c.z - m); e[7] = __expf(c.w - m);
    float s = e[0] + e[1] + e[2] + e[3] + e[4] + e[5] + e[6] + e[7];
#pragma unroll
    for (int off = 32; off > 0; off >>= 1) s += __shfl_xor(s, off, 64);
    float inv = 1.0f / s;
#pragma unroll
    for (int i = 0; i < 8; ++i) e[i] *= inv;
    int b = row >> 9, p = row & 511;
#pragma unroll
    for (int k = 0; k < 3; ++k) {
        const float* cp = chebT + (size_t)k * 262144 + (size_t)p * Nn_ + lane * 8;
        float4 c0 = *(const float4*)cp;
        float4 c1 = *(const float4*)(cp + 4);
        u16x4 o0, o1;
        o0[0] = f2bf(c0.x * e[0]); o0[1] = f2bf(c0.y * e[1]);
        o0[2] = f2bf(c0.z * e[2]); o0[3] = f2bf(c0.w * e[3]);
        o1[0] = f2bf(c1.x * e[4]); o1[1] = f2bf(c1.y * e[5]);
        o1[2] = f2bf(c1.z * e[6]); o1[3] = f2bf(c1.w * e[7]);
        unsigned short* op = AT + (size_t)k * 8388608 + (size_t)b * 262144 + (size_t)p * Nn_ + lane * 8;
        *(u16x4*)op = o0;
        *(u16x4*)(op + 4) = o1;
    }
}

// XT[b][q][m] bf16 = x[b][m][q]
__global__ __launch_bounds__(256) void kxT(const float* __restrict__ x,
                                           unsigned short* __restrict__ XT) {
    __shared__ float tl[64][65];
    int q0 = blockIdx.x * 64, m0 = blockIdx.y * 64, b = blockIdx.z;
    int tid = threadIdx.x, j = tid & 63, i4 = tid >> 6;
#pragma unroll
    for (int r = 0; r < 16; ++r) {
        int i = i4 + r * 4;
        tl[i][j] = x[((size_t)(b * Nn_ + m0 + i)) * 768 + q0 + j];
    }
    __syncthreads();
#pragma unroll
    for (int r = 0; r < 16; ++r) {
        int qq = i4 + r * 4;
        XT[((size_t)b * 768 + q0 + qq) * Nn_ + m0 + j] = f2bf(tl[j][qq]);
    }
}

// H[b][p][q] bf16 = sum_m AT_k[b][p][m] * XT[b][q][m]; grid.z = k*32+b (3 k fused)
__global__ __launch_bounds__(256) void hgemm_mfma(const unsigned short* __restrict__ AT,
                                                  const unsigned short* __restrict__ XT,
                                                  unsigned short* __restrict__ H) {
    __shared__ unsigned short As[512 * 8];
    __shared__ unsigned short Bs[512 * 8];
    int bz = blockIdx.z;
    int b = bz & 31, kk2 = bz >> 5;
    int p0 = blockIdx.y * 128;
    int q0 = blockIdx.x * 128;
    int tid = threadIdx.x;
    int wid = tid >> 6, lane = tid & 63;
    int l15 = lane & 15, l4 = lane >> 4;
    int wm = (wid & 1) * 64, wn = (wid >> 1) * 64;
    const unsigned short* Ab = AT + (size_t)kk2 * 8388608 + (size_t)b * Nn_ * Nn_;
    const unsigned short* Bb = XT + (size_t)b * 768 * Nn_;

    int cp0 = wid * 128 + lane;
    int cp1 = cp0 + 64;
    int rA0 = cp0 >> 2, kA0 = (cp0 & 3) ^ ((rA0 >> 1) & 3);
    int rA1 = cp1 >> 2, kA1 = (cp1 & 3) ^ ((rA1 >> 1) & 3);
    const unsigned short* gA0 = Ab + (size_t)(p0 + rA0) * Nn_ + kA0 * 8;
    const unsigned short* gA1 = Ab + (size_t)(p0 + rA1) * Nn_ + kA1 * 8;
    const unsigned short* gB0 = Bb + (size_t)(q0 + rA0) * Nn_ + kA0 * 8;
    const unsigned short* gB1 = Bb + (size_t)(q0 + rA1) * Nn_ + kA1 * 8;
    unsigned short* lA0 = As + (size_t)(wid * 128) * 8;
    unsigned short* lA1 = As + (size_t)(wid * 128 + 64) * 8;
    unsigned short* lB0 = Bs + (size_t)(wid * 128) * 8;
    unsigned short* lB1 = Bs + (size_t)(wid * 128 + 64) * 8;

    int ca[4], cb[4];
#pragma unroll
    for (int i = 0; i < 4; ++i) {
        int row = wm + i * 16 + l15;
        ca[i] = row * 4 + (l4 ^ ((row >> 1) & 3));
        row = wn + i * 16 + l15;
        cb[i] = row * 4 + (l4 ^ ((row >> 1) & 3));
    }

    f32x4 acc[4][4];
#pragma unroll
    for (int i = 0; i < 4; ++i)
#pragma unroll
        for (int j = 0; j < 4; ++j) acc[i][j] = (f32x4){0.f, 0.f, 0.f, 0.f};

    for (int ks = 0; ks < 16; ++ks) {
        __syncthreads();
        async16(gA0 + ks * 32, lA0);
        async16(gA1 + ks * 32, lA1);
        async16(gB0 + ks * 32, lB0);
        async16(gB1 + ks * 32, lB1);
        __syncthreads();
        bf16x8 af[4], bfv[4];
#pragma unroll
        for (int i = 0; i < 4; ++i) af[i] = *(const bf16x8*)(As + (size_t)ca[i] * 8);
#pragma unroll
        for (int j = 0; j < 4; ++j) bfv[j] = *(const bf16x8*)(Bs + (size_t)cb[j] * 8);
#pragma unroll
        for (int i = 0; i < 4; ++i)
#pragma unroll
            for (int j = 0; j < 4; ++j)
                acc[i][j] = __builtin_amdgcn_mfma_f32_16x16x32_bf16(af[i], bfv[j], acc[i][j], 0, 0, 0);
    }

    unsigned short* Hb = H + (size_t)kk2 * HS_ + (size_t)b * Nn_ * 768;
#pragma unroll
    for (int i = 0; i < 4; ++i)
#pragma unroll
        for (int j = 0; j < 4; ++j) {
            int p = p0 + wm + i * 16 + l4 * 4;
            int q = q0 + wn + j * 16 + l15;
#pragma unroll
            for (int r = 0; r < 4; ++r)
                Hb[(size_t)(p + r) * 768 + q] = f2bf(acc[i][j][r]);
        }
}

// prep: WA[r][kf] bf16 (kf<96: w_cheb[kf][r]; kf>=96: skip_w[r][kf-96])
//       WC[(j*64+c)][g] bf16 = time_w[c][g][j]; also zero tmp for kab atomics
__global__ void kprep(const float* __restrict__ wch, const float* __restrict__ skw,
                      const float* __restrict__ tw,
                      unsigned short* __restrict__ WA, unsigned short* __restrict__ WC,
                      float* __restrict__ tmp) {
    int tid = threadIdx.x;
    for (int i = tid; i < 64 * 128; i += 256) {
        int r = i >> 7, kf = i & 127;
        float v = (kf < 96) ? wch[kf * 64 + r] : skw[r * 32 + (kf - 96)];
        WA[i] = f2bf(v);
    }
    for (int i = tid; i < 192 * 64; i += 256) {
        int j = i / 4096, c = (i >> 6) & 63, g = i & 63;
        WC[i] = f2bf(tw[c * 192 + g * 3 + j]);
    }
    for (int i = tid; i < 24576; i += 256) tmp[i] = 0.f;
}

// -------- fused tail: gcn=relu(H·W), 1x3 conv (3 shifted GEMMs), skip, bias,
// relu, layernorm(c), transposed coalesced store. One block = 1 b x 4 n.
// All LDS in XOR-swizzled 16B chunks (conflict-free scheme proven in hgemm). --
__global__ __launch_bounds__(256) void ktail(const unsigned short* __restrict__ H,
                                             const float* __restrict__ x,
                                             const unsigned short* __restrict__ WA,
                                             const unsigned short* __restrict__ WC,
                                             const float* __restrict__ time_b,
                                             const float* __restrict__ skip_b,
                                             const float* __restrict__ ln_g,
                                             const float* __restrict__ ln_b,
                                             float* __restrict__ out) {
    __shared__ __align__(16) char pool_[24576];            // Hl bf16 96x16 chunks / Tl f32 96x16 chunks
    __shared__ __align__(16) unsigned short Gl[104 * 64];  // 104 rows x 8 chunks x 8 shorts
    __shared__ float biasS[64], lgS[64], lbS[64];
    __shared__ float muS[96], rsS[96];
    unsigned short* Hl = (unsigned short*)pool_;
    float* Tl = (float*)pool_;

    int b = blockIdx.y;
    int n0 = blockIdx.x * 4;
    size_t bn0 = (size_t)b * Nn_ + n0;
    int tid = threadIdx.x;
    int w = tid >> 6, lane = tid & 63, l15 = lane & 15, l4 = lane >> 4;

    // weight fragments (L2-hot, identical across blocks)
    bf16x8 af[4], cf[3][2];
#pragma unroll
    for (int q = 0; q < 4; ++q)
        af[q] = *(const bf16x8*)(WA + (size_t)(16 * w + l15) * 128 + q * 32 + l4 * 8);
#pragma unroll
    for (int j = 0; j < 3; ++j)
#pragma unroll
        for (int kc = 0; kc < 2; ++kc)
            cf[j][kc] = *(const bf16x8*)(WC + (size_t)(j * 64 + 16 * w + l15) * 64 + kc * 32 + l4 * 8);

    // staging: 4x4 register transpose into swizzled Hl[col=(n,t)][kf=(k,f)]
    // unit u = (((k*8+fg)*4+n)*6+tg); k=3 is the x/skip chunk
#pragma unroll
    for (int i = 0; i < 3; ++i) {
        int u = i * 256 + tid;
        int tg = u % 6;
        int r1 = u / 6;
        int n = r1 & 3;
        int r2 = r1 >> 2;
        int fg = r2 & 7;
        int k = r2 >> 3;
        int t0 = tg * 4, f0 = fg * 4;
        u16x4 a0, a1, a2, a3;
        if (k < 3) {
            const unsigned short* hp = H + (size_t)k * HS_ + (bn0 + n) * 768 + f0 * 24 + t0;
            a0 = *(const u16x4*)hp;
            a1 = *(const u16x4*)(hp + 24);
            a2 = *(const u16x4*)(hp + 48);
            a3 = *(const u16x4*)(hp + 72);
        } else {
            const float* xp = x + (bn0 + n) * 768 + f0 * 24 + t0;
            float4 v0 = *(const float4*)xp;
            float4 v1 = *(const float4*)(xp + 24);
            float4 v2 = *(const float4*)(xp + 48);
            float4 v3 = *(const float4*)(xp + 72);
            a0 = (u16x4){f2bf(v0.x), f2bf(v0.y), f2bf(v0.z), f2bf(v0.w)};
            a1 = (u16x4){f2bf(v1.x), f2bf(v1.y), f2bf(v1.z), f2bf(v1.w)};
            a2 = (u16x4){f2bf(v2.x), f2bf(v2.y), f2bf(v2.z), f2bf(v2.w)};
            a3 = (u16x4){f2bf(v3.x), f2bf(v3.y), f2bf(v3.z), f2bf(v3.w)};
        }
        int kc4 = k * 4 + (fg >> 1);
        int half = fg & 1;
#pragma unroll
        for (int s = 0; s < 4; ++s) {
            int col = n * 24 + t0 + s;
            int pos = col * 16 + (kc4 ^ (col & 7));
            u16x4 o = (u16x4){a0[s], a1[s], a2[s], a3[s]};
            *(u16x4*)(Hl + pos * 8 + half * 4) = o;
        }
    }
    // Gl zero borders (tau=0,25 per n) + small params
    if (tid < 64) {
        int n = tid >> 4, rr = (tid >> 3) & 1, gc = tid & 7;
        int row = n * 26 + rr * 25;
        int posg = row * 8 + (gc ^ (row & 7));
        *(float4*)(void*)(Gl + posg * 8) = make_float4(0.f, 0.f, 0.f, 0.f);
        biasS[tid] = time_b[tid] + skip_b[tid];
        lgS[tid] = ln_g[tid];
        lbS[tid] = ln_b[tid];
    }
    __syncthreads();

    // stage 1: gcn (K=96) + skip (K=32), relu(gcn) -> Gl bf16
    f32x4 accs[6];
#pragma unroll
    for (int ct = 0; ct < 6; ++ct) {
        int col = ct * 16 + l15;
        int cx = col & 7;
        bf16x8 h0 = *(const bf16x8*)(Hl + (col * 16 + ((0 + l4) ^ cx)) * 8);
        bf16x8 h1 = *(const bf16x8*)(Hl + (col * 16 + ((4 + l4) ^ cx)) * 8);
        bf16x8 h2 = *(const bf16x8*)(Hl + (col * 16 + ((8 + l4) ^ cx)) * 8);
        bf16x8 h3 = *(const bf16x8*)(Hl + (col * 16 + ((12 + l4) ^ cx)) * 8);
        f32x4 g = (f32x4){0.f, 0.f, 0.f, 0.f};
        g = __builtin_amdgcn_mfma_f32_16x16x32_bf16(af[0], h0, g, 0, 0, 0);
        g = __builtin_amdgcn_mfma_f32_16x16x32_bf16(af[1], h1, g, 0, 0, 0);
        g = __builtin_amdgcn_mfma_f32_16x16x32_bf16(af[2], h2, g, 0, 0, 0);
        f32x4 s = (f32x4){0.f, 0.f, 0.f, 0.f};
        s = __builtin_amdgcn_mfma_f32_16x16x32_bf16(af[3], h3, s, 0, 0, 0);
        accs[ct] = s;
        int n = col / 24, t = col - n * 24;
        int row = n * 26 + t + 1;
        int gc = 2 * w + (l4 >> 1);
        int posg = row * 8 + (gc ^ (row & 7));
        u16x4 pk;
#pragma unroll
        for (int r = 0; r < 4; ++r) pk[r] = f2bf(g[r] > 0.f ? g[r] : 0.f);
        *(u16x4*)(Gl + posg * 8 + (l4 & 1) * 4) = pk;
    }
    __syncthreads();

    // stage 2: conv as 3 shifted GEMMs (K=64) + skip + bias + relu -> Tl fp32
#pragma unroll
    for (int ct = 0; ct < 6; ++ct) {
        int col = ct * 16 + l15;
        int n = col / 24, t = col - n * 24;
        f32x4 acc = accs[ct];
#pragma unroll
        for (int j = 0; j < 3; ++j) {
            int row = n * 26 + t + j;
            int rx = row & 7;
            bf16x8 g0 = *(const bf16x8*)(Gl + (row * 8 + (l4 ^ rx)) * 8);
            bf16x8 g1 = *(const bf16x8*)(Gl + (row * 8 + ((l4 + 4) ^ rx)) * 8);
            acc = __builtin_amdgcn_mfma_f32_16x16x32_bf16(cf[j][0], g0, acc, 0, 0, 0);
            acc = __builtin_amdgcn_mfma_f32_16x16x32_bf16(cf[j][1], g1, acc, 0, 0, 0);
        }
        int cb = 16 * w + 4 * l4;
        f32x4 bv = *(const f32x4*)(biasS + cb);
        f32x4 o;
#pragma unroll
        for (int r = 0; r < 4; ++r) {
            float v = acc[r] + bv[r];
            o[r] = v > 0.f ? v : 0.f;
        }
        int cc = 4 * w + l4;
        int post = col * 16 + (cc ^ (col & 7));
        *(f32x4*)(Tl + post * 4) = o;
    }
    __syncthreads();

    // LN stats per column (n,t)
    if (tid < 96) {
        float sum = 0.f, sq = 0.f;
#pragma unroll
        for (int i = 0; i < 16; ++i) {
            int pos = tid * 16 + (i ^ (tid & 7));
            f32x4 v = *(const f32x4*)(Tl + pos * 4);
#pragma unroll
            for (int r = 0; r < 4; ++r) {
                sum += v[r];
                sq += v[r] * v[r];
            }
        }
        float mu = sum * (1.0f / 64.0f);
        float var = sq * (1.0f / 64.0f) - mu * mu;
        muS[tid] = mu;
        rsS[tid] = rsqrtf(var + 1e-5f);
    }
    __syncthreads();

    // coalesced store: out[((b*N+n)*64+c)*24+t]
    float* ob = out + bn0 * (TC_ * Tt_);
    for (int idx = tid; idx < 6144; idx += 256) {
        int t = idx % 24;
        int c = (idx / 24) & 63;
        int n = idx / 1536;
        int col = n * 24 + t;
        int pos = col * 16 + ((c >> 2) ^ (col & 7));
        float v = Tl[pos * 4 + (c & 3)];
        ob[idx] = (v - muS[col]) * rsS[col] * lgS[c] + lbS[c];
    }
}

extern "C" void kernel_launch(void* const* d_in, const int* in_sizes, int n_in,
                              void* d_out, int out_size, void* d_ws, size_t ws_size,
                              hipStream_t stream) {
    const float* x       = (const float*)d_in[0];
    const float* cheb    = (const float*)d_in[1];
    const float* w_cheb  = (const float*)d_in[2];
    const float* sa_wa   = (const float*)d_in[3];
    const float* sa_wb   = (const float*)d_in[4];
    const float* sa_wc   = (const float*)d_in[5];
    const float* sa_bias = (const float*)d_in[6];
    const float* sa_proj = (const float*)d_in[7];
    const float* ta_w1   = (const float*)d_in[8];
    const float* ta_w2   = (const float*)d_in[9];
    const float* ta_w3   = (const float*)d_in[10];
    const float* ta_bias = (const float*)d_in[11];
    const float* ta_proj = (const float*)d_in[12];
    const float* time_w  = (const float*)d_in[13];
    const float* time_b  = (const float*)d_in[14];
    const float* skip_w  = (const float*)d_in[15];
    const float* skip_b  = (const float*)d_in[16];
    const float* ln_g    = (const float*)d_in[17];
    const float* ln_b    = (const float*)d_in[18];
    float* out = (float*)d_out;

    // ---- workspace layout (~195 MB) ----
    float* cur   = (float*)d_ws;
    float* tmp   = cur;            cur += 24576;
    float* lhs_t = cur;            cur += 393216;
    float* rhs_t = cur;            cur += 393216;
    float* tw    = cur;            cur += 18432;
    float* lhs_s = cur;            cur += 393216;
    float* rhs_s = cur;            cur += 393216;
    unsigned short* WAbuf = (unsigned short*)cur;            // 8192 us
    unsigned short* WCbuf = WAbuf + 8192;                    // 12288 us
    cur += 10240;
    unsigned short* pBh = (unsigned short*)cur;              // 262144 us
    unsigned short* pBl = pBh + 262144;                      // 262144 us
    cur += 262144;
    float* chebT = cur;            cur += 786432;
    unsigned short* regionA = (unsigned short*)cur;          // attnT hi/lo, then AT x3
    unsigned short* aTh = regionA;
    unsigned short* aTl = regionA + 8388608;
    unsigned short* ATb = regionA;
    cur += 12582912;
    float* STbuf = cur;            cur += 8388608;
    unsigned short* XT = (unsigned short*)cur;               // 12582912 us
    cur += 6291456;
    unsigned short* hbuf = (unsigned short*)cur;             // 37748736 us

    kprep<<<1, 256, 0, stream>>>(w_cheb, skip_w, time_w, WAbuf, WCbuf, tmp);
    kprojsplit<<<1024, 256, 0, stream>>>(sa_proj, pBh, pBl);
    kchebT<<<dim3(8, 8, 3), 256, 0, stream>>>(cheb, chebT);
    kxT<<<dim3(12, 8, 32), 256, 0, stream>>>(x, XT);
    kab<<<dim3(16, 32), 256, 0, stream>>>(x, ta_w1, ta_w3, tmp, rhs_t);
    kc_lhs<<<1536, 256, 0, stream>>>(tmp, ta_w2, lhs_t);
    kd_temporal<<<32, 576, 0, stream>>>(lhs_t, rhs_t, ta_bias, ta_proj, tw);
    ke_spatial<<<dim3(512, 32), 256, 0, stream>>>(x, tw, sa_wa, sa_wb, sa_wc, lhs_s, rhs_s);
    kg_attnT<<<dim3(64, 32), 256, 0, stream>>>(lhs_s, rhs_s, sa_bias, aTh, aTl);
    ksgemm_mfma<<<dim3(4, 4, 32), 256, 0, stream>>>(aTh, aTl, pBh, pBl, STbuf);
    kjaT<<<4096, 256, 0, stream>>>(STbuf, chebT, ATb);
    hgemm_mfma<<<dim3(6, 4, 96), 256, 0, stream>>>(ATb, XT, hbuf);
    ktail<<<dim3(128, 32), 256, 0, stream>>>(hbuf, x, WAbuf, WCbuf,
                                             time_b, skip_b, ln_g, ln_b, out);
}